// Round 1
// baseline (3095.262 us; speedup 1.0000x reference)
//
#include <hip/hip_runtime.h>

#define N_NODES 50000
#define N_EDGES 800000
#define ND 128
#define ED 32
#define AD 128
#define CAT 288   // 2*ND + ED
#define G3 384    // 3*ND

#define ETILE 16  // edges per block-tile
#define NT 8      // nodes per block-tile (GRU)

// ---------------------------------------------------------------------------
// Edge kernel: msg = [hv[src], hv[dst], he] @ W (288x128) + b, atomicAdd to
// accum[dst]. One thread per output column j (block=128), 16 edges per tile.
// ---------------------------------------------------------------------------
__global__ __launch_bounds__(128) void edge_msg_kernel(
    const float* __restrict__ hv, const float* __restrict__ he,
    const int* __restrict__ src, const int* __restrict__ dst,
    const float* __restrict__ W, const float* __restrict__ b,
    float* __restrict__ accum)
{
    __shared__ float xs[ETILE][CAT];
    __shared__ int ssrc[ETILE];
    __shared__ int sdst[ETILE];
    const int j = threadIdx.x;
    const int ntiles = N_EDGES / ETILE;  // 50000, divides exactly

    for (int tile = blockIdx.x; tile < ntiles; tile += gridDim.x) {
        const int e0 = tile * ETILE;
        if (j < ETILE) {
            ssrc[j] = src[e0 + j];
            sdst[j] = dst[e0 + j];
        }
        __syncthreads();

        // Stage x rows: hv[src] (128), hv[dst] (128), he (32) per edge.
        #pragma unroll
        for (int e = 0; e < ETILE; ++e) {
            xs[e][j]      = hv[ssrc[e] * ND + j];
            xs[e][ND + j] = hv[sdst[e] * ND + j];
        }
        // he: ETILE*32 = 512 consecutive floats, coalesced.
        #pragma unroll
        for (int r = 0; r < (ETILE * ED) / 128; ++r) {
            const int idx = r * 128 + j;
            xs[idx >> 5][2 * ND + (idx & 31)] = he[e0 * ED + idx];
        }
        __syncthreads();

        float acc[ETILE];
        #pragma unroll
        for (int e = 0; e < ETILE; ++e) acc[e] = b[j];

        const float* wp = W + j;
        for (int k = 0; k < CAT; k += 4) {
            const float w0 = wp[0 * AD];
            const float w1 = wp[1 * AD];
            const float w2 = wp[2 * AD];
            const float w3 = wp[3 * AD];
            wp += 4 * AD;
            #pragma unroll
            for (int e = 0; e < ETILE; ++e) {
                const float4 x = *(const float4*)(&xs[e][k]);
                acc[e] = fmaf(x.w, w3, fmaf(x.z, w2,
                         fmaf(x.y, w1, fmaf(x.x, w0, acc[e]))));
            }
        }

        #pragma unroll
        for (int e = 0; e < ETILE; ++e) {
            atomicAdd(&accum[sdst[e] * ND + j], acc[e]);
        }
        __syncthreads();
    }
}

// ---------------------------------------------------------------------------
// GRU kernel: gi = a @ W_ih + b_ih, gh = h @ W_hh + b_hh (both 128->384),
// then gates. One thread per gate column (block=384), 8 nodes per tile.
// ---------------------------------------------------------------------------
__global__ __launch_bounds__(384) void gru_kernel(
    const float* __restrict__ a_in, const float* __restrict__ h_in,
    const float* __restrict__ W_ih, const float* __restrict__ W_hh,
    const float* __restrict__ b_ih, const float* __restrict__ b_hh,
    float* __restrict__ h_out)
{
    __shared__ float xs[NT][ND];
    __shared__ float hs[NT][ND];
    __shared__ float gs[NT][2 * G3];
    const int j = threadIdx.x;
    const int ntiles = (N_NODES + NT - 1) / NT;  // 6250, divides exactly

    for (int tile = blockIdx.x; tile < ntiles; tile += gridDim.x) {
        const int n0 = tile * NT;
        for (int idx = j; idx < NT * ND; idx += 384) {
            const int e = idx >> 7, c = idx & 127;
            const int n = n0 + e;
            float av = 0.f, hvv = 0.f;
            if (n < N_NODES) {
                av  = a_in[n * ND + c];
                hvv = h_in[n * ND + c];
            }
            xs[e][c] = av;
            hs[e][c] = hvv;
        }
        __syncthreads();

        float ai[NT], ah[NT];
        #pragma unroll
        for (int e = 0; e < NT; ++e) { ai[e] = b_ih[j]; ah[e] = b_hh[j]; }

        const float* wip = W_ih + j;
        const float* whp = W_hh + j;
        for (int k = 0; k < ND; k += 4) {
            const float wi0 = wip[0 * G3], wi1 = wip[1 * G3];
            const float wi2 = wip[2 * G3], wi3 = wip[3 * G3];
            const float wh0 = whp[0 * G3], wh1 = whp[1 * G3];
            const float wh2 = whp[2 * G3], wh3 = whp[3 * G3];
            wip += 4 * G3; whp += 4 * G3;
            #pragma unroll
            for (int e = 0; e < NT; ++e) {
                const float4 x = *(const float4*)(&xs[e][k]);
                const float4 h = *(const float4*)(&hs[e][k]);
                ai[e] = fmaf(x.w, wi3, fmaf(x.z, wi2,
                        fmaf(x.y, wi1, fmaf(x.x, wi0, ai[e]))));
                ah[e] = fmaf(h.w, wh3, fmaf(h.z, wh2,
                        fmaf(h.y, wh1, fmaf(h.x, wh0, ah[e]))));
            }
        }

        #pragma unroll
        for (int e = 0; e < NT; ++e) {
            gs[e][j]      = ai[e];
            gs[e][G3 + j] = ah[e];
        }
        __syncthreads();

        for (int idx = j; idx < NT * ND; idx += 384) {
            const int e = idx >> 7, c = idx & 127;
            const int n = n0 + e;
            if (n < N_NODES) {
                const float ir  = gs[e][c];
                const float iz  = gs[e][ND + c];
                const float inn = gs[e][2 * ND + c];
                const float hr  = gs[e][G3 + c];
                const float hz  = gs[e][G3 + ND + c];
                const float hn  = gs[e][G3 + 2 * ND + c];
                const float r = 1.f / (1.f + expf(-(ir + hr)));
                const float z = 1.f / (1.f + expf(-(iz + hz)));
                const float nn = tanhf(inn + r * hn);
                h_out[n * ND + c] = (1.f - z) * nn + z * hs[e][c];
            }
        }
        __syncthreads();
    }
}

// ---------------------------------------------------------------------------
extern "C" void kernel_launch(void* const* d_in, const int* in_sizes, int n_in,
                              void* d_out, int out_size, void* d_ws, size_t ws_size,
                              hipStream_t stream)
{
    const float* hv   = (const float*)d_in[0];
    const float* he   = (const float*)d_in[1];
    const int*   src  = (const int*)d_in[2];
    const int*   dst  = (const int*)d_in[3];
    const float* Wmsg = (const float*)d_in[4];
    const float* bmsg = (const float*)d_in[5];
    const float* Wih  = (const float*)d_in[6];
    const float* Whh  = (const float*)d_in[7];
    const float* bih  = (const float*)d_in[8];
    const float* bhh  = (const float*)d_in[9];
    float* out   = (float*)d_out;
    float* accum = (float*)d_ws;  // N_NODES * ND floats = 25.6 MB
    const size_t accum_bytes = (size_t)N_NODES * ND * sizeof(float);

    const int edge_blocks = N_EDGES / ETILE;           // 50000
    const int gru_blocks  = (N_NODES + NT - 1) / NT;   // 6250

    for (int t = 0; t < 2; ++t) {
        const float* h_cur = (t == 0) ? hv : out;
        hipMemsetAsync(accum, 0, accum_bytes, stream);
        edge_msg_kernel<<<edge_blocks, 128, 0, stream>>>(
            h_cur, he, src, dst,
            Wmsg + (size_t)t * CAT * AD, bmsg + (size_t)t * AD, accum);
        gru_kernel<<<gru_blocks, 384, 0, stream>>>(
            accum, h_cur,
            Wih + (size_t)t * ND * G3, Whh + (size_t)t * ND * G3,
            bih + (size_t)t * G3, bhh + (size_t)t * G3, out);
    }
}

// Round 3
// 1423.626 us; speedup vs baseline: 2.1742x; 2.1742x over previous
//
#include <hip/hip_runtime.h>

#define N_NODES 50000
#define N_EDGES 800000
#define ND 128
#define ED 32
#define AD 128
#define CAT 288   // 2*ND + ED
#define G3 384    // 3*ND

#define MT 32         // edges per MFMA tile
#define XPAD 296      // LDS row stride (bf16 elems): 592B, 16B-aligned, 2-way banks
#define KSTEPS 9      // 288 / 32
#define NT 8          // nodes per block-tile (GRU)

typedef __attribute__((ext_vector_type(8))) short bfrag;   // 8 bf16 (4 VGPRs)
typedef __attribute__((ext_vector_type(4))) float f32x4;   // MFMA accumulator

__device__ __forceinline__ unsigned int f2bf(float f) {
    unsigned int u = __float_as_uint(f);
    return (u + 0x7FFFu + ((u >> 16) & 1u)) >> 16;   // RTNE to bf16
}
// split a pair of floats into packed-bf16 hi and lo (residual) words
__device__ __forceinline__ void split2(float a, float b,
                                       unsigned int& hi, unsigned int& lo) {
    const unsigned int ha = f2bf(a), hb = f2bf(b);
    const float ra = a - __uint_as_float(ha << 16);
    const float rb = b - __uint_as_float(hb << 16);
    hi = ha | (hb << 16);
    lo = f2bf(ra) | (f2bf(rb) << 16);
}

// ---------------------------------------------------------------------------
// Convert + transpose W_msg (2 x 288 x 128 fp32) -> Wt_hi / Wt_lo
// (each 2 x 128 x 288 bf16)
// ---------------------------------------------------------------------------
__global__ __launch_bounds__(256) void convert_w_kernel(
    const float* __restrict__ W,
    unsigned short* __restrict__ Wt_hi, unsigned short* __restrict__ Wt_lo)
{
    const int id = blockIdx.x * 256 + threadIdx.x;   // 2*288*128 = 73728 ids
    if (id >= 2 * CAT * AD) return;
    const int n = id & (AD - 1);
    const int k = (id >> 7) % CAT;
    const int t = id / (CAT * AD);
    const float w = W[(size_t)t * CAT * AD + (size_t)k * AD + n];
    const unsigned int hi = f2bf(w);
    const float r = w - __uint_as_float(hi << 16);
    const size_t o = (size_t)t * AD * CAT + (size_t)n * CAT + k;
    Wt_hi[o] = (unsigned short)hi;
    Wt_lo[o] = (unsigned short)f2bf(r);
}

// ---------------------------------------------------------------------------
// Edge kernel (MFMA, bf16x2 split precision):
// msg = [hv[src], hv[dst], he] @ W + b  computed as
//   x_hi·W_hi + x_lo·W_hi + x_hi·W_lo  (fp32 accumulate), atomic scatter.
// 256 threads = 4 waves; tile = 32 edges x 128 cols; wave w owns cols
// [32w, 32w+32). All B fragments (hi+lo) register-resident.
// ---------------------------------------------------------------------------
__global__ __launch_bounds__(256, 2) void edge_mfma_kernel(
    const float* __restrict__ hv, const float* __restrict__ he,
    const int* __restrict__ src, const int* __restrict__ dst,
    const unsigned short* __restrict__ Wt_hi,
    const unsigned short* __restrict__ Wt_lo,
    const float* __restrict__ b,
    float* __restrict__ accum)
{
    __shared__ unsigned short xh[MT][XPAD];
    __shared__ unsigned short xl[MT][XPAD];
    __shared__ int sdst_sh[MT];

    const int t    = threadIdx.x;
    const int wave = t >> 6;
    const int lane = t & 63;
    const int kq   = lane >> 4;   // 0..3: k-quad
    const int lr   = lane & 15;   // row (A) / col (B,C)

    // Preload B fragments (hi and lo sets).
    bfrag bh[2][KSTEPS], bl[2][KSTEPS];
    float bias[2];
    #pragma unroll
    for (int nt = 0; nt < 2; ++nt) {
        const int n = wave * 32 + nt * 16 + lr;
        bias[nt] = b[n];
        const unsigned short* ph = Wt_hi + (size_t)n * CAT + kq * 8;
        const unsigned short* pl = Wt_lo + (size_t)n * CAT + kq * 8;
        #pragma unroll
        for (int ks = 0; ks < KSTEPS; ++ks) {
            bh[nt][ks] = *(const bfrag*)(ph + ks * 32);
            bl[nt][ks] = *(const bfrag*)(pl + ks * 32);
        }
    }

    // Staging geometry: thread t stages edge e = t>>3, chunk c = t&7.
    const int e = t >> 3, c = t & 7;
    const int ntiles = N_EDGES / MT;   // 25000

    for (int tile = blockIdx.x; tile < ntiles; tile += gridDim.x) {
        const int e0 = tile * MT;

        if (t < MT) sdst_sh[t] = dst[e0 + t];
        const int se = src[e0 + e];
        const int de = dst[e0 + e];

        // hv[src] row: 16 floats -> hi/lo bf16x16
        {
            const float4* p4 = (const float4*)(hv + (size_t)se * ND + c * 16);
            float4 a0 = p4[0], a1 = p4[1], a2 = p4[2], a3 = p4[3];
            uint4 h0, h1, l0, l1;
            split2(a0.x, a0.y, h0.x, l0.x); split2(a0.z, a0.w, h0.y, l0.y);
            split2(a1.x, a1.y, h0.z, l0.z); split2(a1.z, a1.w, h0.w, l0.w);
            split2(a2.x, a2.y, h1.x, l1.x); split2(a2.z, a2.w, h1.y, l1.y);
            split2(a3.x, a3.y, h1.z, l1.z); split2(a3.z, a3.w, h1.w, l1.w);
            *(uint4*)&xh[e][c * 16]     = h0;  *(uint4*)&xh[e][c * 16 + 8] = h1;
            *(uint4*)&xl[e][c * 16]     = l0;  *(uint4*)&xl[e][c * 16 + 8] = l1;
        }
        // hv[dst] row
        {
            const float4* p4 = (const float4*)(hv + (size_t)de * ND + c * 16);
            float4 a0 = p4[0], a1 = p4[1], a2 = p4[2], a3 = p4[3];
            uint4 h0, h1, l0, l1;
            split2(a0.x, a0.y, h0.x, l0.x); split2(a0.z, a0.w, h0.y, l0.y);
            split2(a1.x, a1.y, h0.z, l0.z); split2(a1.z, a1.w, h0.w, l0.w);
            split2(a2.x, a2.y, h1.x, l1.x); split2(a2.z, a2.w, h1.y, l1.y);
            split2(a3.x, a3.y, h1.z, l1.z); split2(a3.z, a3.w, h1.w, l1.w);
            *(uint4*)&xh[e][ND + c * 16]     = h0;  *(uint4*)&xh[e][ND + c * 16 + 8] = h1;
            *(uint4*)&xl[e][ND + c * 16]     = l0;  *(uint4*)&xl[e][ND + c * 16 + 8] = l1;
        }
        // he row: 4 floats
        {
            const float4 h4 = *(const float4*)(he + (size_t)(e0 + e) * ED + c * 4);
            uint2 h0, l0;
            split2(h4.x, h4.y, h0.x, l0.x); split2(h4.z, h4.w, h0.y, l0.y);
            *(uint2*)&xh[e][2 * ND + c * 4] = h0;
            *(uint2*)&xl[e][2 * ND + c * 4] = l0;
        }
        __syncthreads();

        f32x4 acc00 = {0.f, 0.f, 0.f, 0.f}, acc01 = {0.f, 0.f, 0.f, 0.f};
        f32x4 acc10 = {0.f, 0.f, 0.f, 0.f}, acc11 = {0.f, 0.f, 0.f, 0.f};
        #pragma unroll
        for (int ks = 0; ks < KSTEPS; ++ks) {
            const int ko = ks * 32 + kq * 8;
            const bfrag a0h = *(const bfrag*)&xh[lr][ko];
            const bfrag a0l = *(const bfrag*)&xl[lr][ko];
            const bfrag a1h = *(const bfrag*)&xh[16 + lr][ko];
            const bfrag a1l = *(const bfrag*)&xl[16 + lr][ko];
            acc00 = __builtin_amdgcn_mfma_f32_16x16x32_bf16(a0h, bh[0][ks], acc00, 0, 0, 0);
            acc00 = __builtin_amdgcn_mfma_f32_16x16x32_bf16(a0l, bh[0][ks], acc00, 0, 0, 0);
            acc00 = __builtin_amdgcn_mfma_f32_16x16x32_bf16(a0h, bl[0][ks], acc00, 0, 0, 0);
            acc01 = __builtin_amdgcn_mfma_f32_16x16x32_bf16(a0h, bh[1][ks], acc01, 0, 0, 0);
            acc01 = __builtin_amdgcn_mfma_f32_16x16x32_bf16(a0l, bh[1][ks], acc01, 0, 0, 0);
            acc01 = __builtin_amdgcn_mfma_f32_16x16x32_bf16(a0h, bl[1][ks], acc01, 0, 0, 0);
            acc10 = __builtin_amdgcn_mfma_f32_16x16x32_bf16(a1h, bh[0][ks], acc10, 0, 0, 0);
            acc10 = __builtin_amdgcn_mfma_f32_16x16x32_bf16(a1l, bh[0][ks], acc10, 0, 0, 0);
            acc10 = __builtin_amdgcn_mfma_f32_16x16x32_bf16(a1h, bl[0][ks], acc10, 0, 0, 0);
            acc11 = __builtin_amdgcn_mfma_f32_16x16x32_bf16(a1h, bh[1][ks], acc11, 0, 0, 0);
            acc11 = __builtin_amdgcn_mfma_f32_16x16x32_bf16(a1l, bh[1][ks], acc11, 0, 0, 0);
            acc11 = __builtin_amdgcn_mfma_f32_16x16x32_bf16(a1h, bl[1][ks], acc11, 0, 0, 0);
        }

        // Epilogue: C/D layout col = lane&15, row = (lane>>4)*4 + reg.
        #pragma unroll
        for (int r = 0; r < 4; ++r) {
            const int row0 = kq * 4 + r;        // m-tile 0
            const int row1 = 16 + kq * 4 + r;   // m-tile 1
            const int d0 = sdst_sh[row0];
            const int d1 = sdst_sh[row1];
            const int n0 = wave * 32 + lr;
            const int n1 = wave * 32 + 16 + lr;
            atomicAdd(&accum[(size_t)d0 * ND + n0], acc00[r] + bias[0]);
            atomicAdd(&accum[(size_t)d0 * ND + n1], acc01[r] + bias[1]);
            atomicAdd(&accum[(size_t)d1 * ND + n0], acc10[r] + bias[0]);
            atomicAdd(&accum[(size_t)d1 * ND + n1], acc11[r] + bias[1]);
        }
        __syncthreads();
    }
}

// ---------------------------------------------------------------------------
// GRU kernel (fp32, unchanged from R0 baseline)
// ---------------------------------------------------------------------------
__global__ __launch_bounds__(384) void gru_kernel(
    const float* __restrict__ a_in, const float* __restrict__ h_in,
    const float* __restrict__ W_ih, const float* __restrict__ W_hh,
    const float* __restrict__ b_ih, const float* __restrict__ b_hh,
    float* __restrict__ h_out)
{
    __shared__ float xs[NT][ND];
    __shared__ float hs[NT][ND];
    __shared__ float gs[NT][2 * G3];
    const int j = threadIdx.x;
    const int ntiles = (N_NODES + NT - 1) / NT;

    for (int tile = blockIdx.x; tile < ntiles; tile += gridDim.x) {
        const int n0 = tile * NT;
        for (int idx = j; idx < NT * ND; idx += 384) {
            const int e = idx >> 7, cc = idx & 127;
            const int n = n0 + e;
            float av = 0.f, hvv = 0.f;
            if (n < N_NODES) {
                av  = a_in[n * ND + cc];
                hvv = h_in[n * ND + cc];
            }
            xs[e][cc] = av;
            hs[e][cc] = hvv;
        }
        __syncthreads();

        float ai[NT], ah[NT];
        #pragma unroll
        for (int e = 0; e < NT; ++e) { ai[e] = b_ih[j]; ah[e] = b_hh[j]; }

        const float* wip = W_ih + j;
        const float* whp = W_hh + j;
        for (int k = 0; k < ND; k += 4) {
            const float wi0 = wip[0 * G3], wi1 = wip[1 * G3];
            const float wi2 = wip[2 * G3], wi3 = wip[3 * G3];
            const float wh0 = whp[0 * G3], wh1 = whp[1 * G3];
            const float wh2 = whp[2 * G3], wh3 = whp[3 * G3];
            wip += 4 * G3; whp += 4 * G3;
            #pragma unroll
            for (int e = 0; e < NT; ++e) {
                const float4 x = *(const float4*)(&xs[e][k]);
                const float4 h = *(const float4*)(&hs[e][k]);
                ai[e] = fmaf(x.w, wi3, fmaf(x.z, wi2,
                        fmaf(x.y, wi1, fmaf(x.x, wi0, ai[e]))));
                ah[e] = fmaf(h.w, wh3, fmaf(h.z, wh2,
                        fmaf(h.y, wh1, fmaf(h.x, wh0, ah[e]))));
            }
        }

        #pragma unroll
        for (int e = 0; e < NT; ++e) {
            gs[e][j]      = ai[e];
            gs[e][G3 + j] = ah[e];
        }
        __syncthreads();

        for (int idx = j; idx < NT * ND; idx += 384) {
            const int e = idx >> 7, cc = idx & 127;
            const int n = n0 + e;
            if (n < N_NODES) {
                const float ir  = gs[e][cc];
                const float iz  = gs[e][ND + cc];
                const float inn = gs[e][2 * ND + cc];
                const float hr  = gs[e][G3 + cc];
                const float hz  = gs[e][G3 + ND + cc];
                const float hn  = gs[e][G3 + 2 * ND + cc];
                const float r = 1.f / (1.f + expf(-(ir + hr)));
                const float z = 1.f / (1.f + expf(-(iz + hz)));
                const float nn = tanhf(inn + r * hn);
                h_out[n * ND + cc] = (1.f - z) * nn + z * hs[e][cc];
            }
        }
        __syncthreads();
    }
}

// ---------------------------------------------------------------------------
extern "C" void kernel_launch(void* const* d_in, const int* in_sizes, int n_in,
                              void* d_out, int out_size, void* d_ws, size_t ws_size,
                              hipStream_t stream)
{
    const float* hv   = (const float*)d_in[0];
    const float* he   = (const float*)d_in[1];
    const int*   src  = (const int*)d_in[2];
    const int*   dst  = (const int*)d_in[3];
    const float* Wmsg = (const float*)d_in[4];
    const float* bmsg = (const float*)d_in[5];
    const float* Wih  = (const float*)d_in[6];
    const float* Whh  = (const float*)d_in[7];
    const float* bih  = (const float*)d_in[8];
    const float* bhh  = (const float*)d_in[9];
    float* out   = (float*)d_out;

    float* accum = (float*)d_ws;                        // 25.6 MB fp32
    const size_t accum_bytes = (size_t)N_NODES * ND * sizeof(float);
    unsigned short* Wt_hi = (unsigned short*)((char*)d_ws + accum_bytes);
    unsigned short* Wt_lo = Wt_hi + (size_t)2 * AD * CAT;

    convert_w_kernel<<<(2 * CAT * AD + 255) / 256, 256, 0, stream>>>(Wmsg, Wt_hi, Wt_lo);

    const int gru_blocks = (N_NODES + NT - 1) / NT;   // 6250

    for (int t = 0; t < 2; ++t) {
        const float* h_cur = (t == 0) ? hv : out;
        hipMemsetAsync(accum, 0, accum_bytes, stream);
        edge_mfma_kernel<<<2048, 256, 0, stream>>>(
            h_cur, he, src, dst,
            Wt_hi + (size_t)t * AD * CAT, Wt_lo + (size_t)t * AD * CAT,
            bmsg + (size_t)t * AD, accum);
        gru_kernel<<<gru_blocks, 384, 0, stream>>>(
            accum, h_cur,
            Wih + (size_t)t * ND * G3, Whh + (size_t)t * ND * G3,
            bih + (size_t)t * G3, bhh + (size_t)t * G3, out);
    }
}

// Round 4
// 1064.776 us; speedup vs baseline: 2.9070x; 1.3370x over previous
//
#include <hip/hip_runtime.h>

#define N_NODES 50000
#define N_EDGES 800000
#define ND 128
#define ED 32
#define AD 128
#define CAT 288   // 2*ND + ED
#define G3 384    // 3*ND

#define MT 32         // edges per MFMA tile
#define XPAD 296      // LDS row stride (bf16 elems), 16B-aligned
#define KSTEPS 9      // 288 / 32

typedef unsigned short ushort_t;
typedef __attribute__((ext_vector_type(8))) short bfrag;   // 8 bf16 (4 VGPRs)
typedef __attribute__((ext_vector_type(4))) float f32x4;   // MFMA accumulator

__device__ __forceinline__ unsigned int f2bf(float f) {
    unsigned int u = __float_as_uint(f);
    return (u + 0x7FFFu + ((u >> 16) & 1u)) >> 16;   // RTNE to bf16
}
__device__ __forceinline__ void split2(float a, float b,
                                       unsigned int& hi, unsigned int& lo) {
    const unsigned int ha = f2bf(a), hb = f2bf(b);
    const float ra = a - __uint_as_float(ha << 16);
    const float rb = b - __uint_as_float(hb << 16);
    hi = ha | (hb << 16);
    lo = f2bf(ra) | (f2bf(rb) << 16);
}

// ---------------------------------------------------------------------------
// Split fp32 array -> bf16 hi/lo arrays (vectorized x4).
// ---------------------------------------------------------------------------
__global__ __launch_bounds__(256) void split_f32_kernel(
    const float* __restrict__ x, ushort_t* __restrict__ hi,
    ushort_t* __restrict__ lo, int n4)
{
    const int id = blockIdx.x * 256 + threadIdx.x;
    if (id >= n4) return;
    const float4 v = ((const float4*)x)[id];
    uint2 h, l;
    split2(v.x, v.y, h.x, l.x); split2(v.z, v.w, h.y, l.y);
    ((uint2*)hi)[id] = h; ((uint2*)lo)[id] = l;
}

// ---------------------------------------------------------------------------
// Convert + transpose W_msg (2 x 288 x 128) -> Wt_hi/Wt_lo (2 x 128 x 288 bf16)
// ---------------------------------------------------------------------------
__global__ __launch_bounds__(256) void convert_w_kernel(
    const float* __restrict__ W,
    ushort_t* __restrict__ Wt_hi, ushort_t* __restrict__ Wt_lo)
{
    const int id = blockIdx.x * 256 + threadIdx.x;   // 2*288*128 = 73728
    if (id >= 2 * CAT * AD) return;
    const int n = id & (AD - 1);
    const int k = (id >> 7) % CAT;
    const int t = id / (CAT * AD);
    const float w = W[(size_t)t * CAT * AD + (size_t)k * AD + n];
    const unsigned int hi = f2bf(w);
    const float r = w - __uint_as_float(hi << 16);
    const size_t o = (size_t)t * AD * CAT + (size_t)n * CAT + k;
    Wt_hi[o] = (ushort_t)hi;
    Wt_lo[o] = (ushort_t)f2bf(r);
}

// ---------------------------------------------------------------------------
// Convert gate weights W_ih/W_hh (2 x 128 x 384) into MFMA-fragment-swizzled
// bf16 hi/lo: layout [t][nt(24)][ks(4)][kq(4)][lr(16)][j(8)] so that a wave's
// fragment load for (nt,ks) is one contiguous 1KB region.
// ---------------------------------------------------------------------------
__global__ __launch_bounds__(256) void convert_gatew_kernel(
    const float* __restrict__ W_ih, const float* __restrict__ W_hh,
    ushort_t* __restrict__ Bih_hi, ushort_t* __restrict__ Bih_lo,
    ushort_t* __restrict__ Bhh_hi, ushort_t* __restrict__ Bhh_lo)
{
    const int id = blockIdx.x * 256 + threadIdx.x;   // 2*2*49152 = 196608
    if (id >= 196608) return;
    const int t   = id / 98304;
    const int rem = id % 98304;
    const int mat = rem / 49152;
    const int q   = rem % 49152;
    const int nt = q / 2048,  r1 = q % 2048;
    const int ks = r1 / 512,  r2 = r1 % 512;
    const int kq = r2 / 128,  r3 = r2 % 128;
    const int lr = r3 / 8,    j  = r3 % 8;
    const int n = nt * 16 + lr;
    const int k = ks * 32 + kq * 8 + j;
    const float* W = mat ? W_hh : W_ih;
    const float w = W[(size_t)t * ND * G3 + (size_t)k * G3 + n];
    const unsigned int hi = f2bf(w);
    const float res = w - __uint_as_float(hi << 16);
    const size_t o = (size_t)t * 49152 + q;
    if (mat) { Bhh_hi[o] = (ushort_t)hi; Bhh_lo[o] = (ushort_t)f2bf(res); }
    else     { Bih_hi[o] = (ushort_t)hi; Bih_lo[o] = (ushort_t)f2bf(res); }
}

// ---------------------------------------------------------------------------
// Edge kernel (MFMA, bf16x2): reads PRE-SPLIT hv_hi/hv_lo (no per-edge cvt).
// msg = x_hi·W_hi + x_lo·W_hi + x_hi·W_lo + b, atomic scatter to accum[dst].
// ---------------------------------------------------------------------------
__global__ __launch_bounds__(256, 2) void edge_mfma_kernel(
    const ushort_t* __restrict__ hv_hi, const ushort_t* __restrict__ hv_lo,
    const float* __restrict__ he,
    const int* __restrict__ src, const int* __restrict__ dst,
    const ushort_t* __restrict__ Wt_hi, const ushort_t* __restrict__ Wt_lo,
    const float* __restrict__ b,
    float* __restrict__ accum)
{
    __shared__ ushort_t xh[MT][XPAD];
    __shared__ ushort_t xl[MT][XPAD];
    __shared__ int sdst_sh[MT];

    const int t    = threadIdx.x;
    const int wave = t >> 6;
    const int lane = t & 63;
    const int kq   = lane >> 4;
    const int lr   = lane & 15;

    bfrag bh[2][KSTEPS], bl[2][KSTEPS];
    float bias[2];
    #pragma unroll
    for (int nt = 0; nt < 2; ++nt) {
        const int n = wave * 32 + nt * 16 + lr;
        bias[nt] = b[n];
        const ushort_t* ph = Wt_hi + (size_t)n * CAT + kq * 8;
        const ushort_t* pl = Wt_lo + (size_t)n * CAT + kq * 8;
        #pragma unroll
        for (int ks = 0; ks < KSTEPS; ++ks) {
            bh[nt][ks] = *(const bfrag*)(ph + ks * 32);
            bl[nt][ks] = *(const bfrag*)(pl + ks * 32);
        }
    }

    const int e = t >> 3, c = t & 7;
    const int ntiles = N_EDGES / MT;   // 25000

    for (int tile = blockIdx.x; tile < ntiles; tile += gridDim.x) {
        const int e0 = tile * MT;

        if (t < MT) sdst_sh[t] = dst[e0 + t];
        const int se = src[e0 + e];
        const int de = dst[e0 + e];

        // hv[src]: 16 bf16 hi + 16 lo (pure copies)
        {
            const uint4* ph = (const uint4*)(hv_hi + (size_t)se * ND + c * 16);
            const uint4* pl = (const uint4*)(hv_lo + (size_t)se * ND + c * 16);
            *(uint4*)&xh[e][c * 16]     = ph[0];  *(uint4*)&xh[e][c * 16 + 8] = ph[1];
            *(uint4*)&xl[e][c * 16]     = pl[0];  *(uint4*)&xl[e][c * 16 + 8] = pl[1];
        }
        // hv[dst]
        {
            const uint4* ph = (const uint4*)(hv_hi + (size_t)de * ND + c * 16);
            const uint4* pl = (const uint4*)(hv_lo + (size_t)de * ND + c * 16);
            *(uint4*)&xh[e][ND + c * 16]     = ph[0];  *(uint4*)&xh[e][ND + c * 16 + 8] = ph[1];
            *(uint4*)&xl[e][ND + c * 16]     = pl[0];  *(uint4*)&xl[e][ND + c * 16 + 8] = pl[1];
        }
        // he: 4 floats, split in-kernel (cheap)
        {
            const float4 h4 = *(const float4*)(he + (size_t)(e0 + e) * ED + c * 4);
            uint2 h0, l0;
            split2(h4.x, h4.y, h0.x, l0.x); split2(h4.z, h4.w, h0.y, l0.y);
            *(uint2*)&xh[e][2 * ND + c * 4] = h0;
            *(uint2*)&xl[e][2 * ND + c * 4] = l0;
        }
        __syncthreads();

        f32x4 acc00 = {0.f,0.f,0.f,0.f}, acc01 = {0.f,0.f,0.f,0.f};
        f32x4 acc10 = {0.f,0.f,0.f,0.f}, acc11 = {0.f,0.f,0.f,0.f};
        #pragma unroll
        for (int ks = 0; ks < KSTEPS; ++ks) {
            const int ko = ks * 32 + kq * 8;
            const bfrag a0h = *(const bfrag*)&xh[lr][ko];
            const bfrag a0l = *(const bfrag*)&xl[lr][ko];
            const bfrag a1h = *(const bfrag*)&xh[16 + lr][ko];
            const bfrag a1l = *(const bfrag*)&xl[16 + lr][ko];
            acc00 = __builtin_amdgcn_mfma_f32_16x16x32_bf16(a0h, bh[0][ks], acc00, 0, 0, 0);
            acc00 = __builtin_amdgcn_mfma_f32_16x16x32_bf16(a0l, bh[0][ks], acc00, 0, 0, 0);
            acc00 = __builtin_amdgcn_mfma_f32_16x16x32_bf16(a0h, bl[0][ks], acc00, 0, 0, 0);
            acc01 = __builtin_amdgcn_mfma_f32_16x16x32_bf16(a0h, bh[1][ks], acc01, 0, 0, 0);
            acc01 = __builtin_amdgcn_mfma_f32_16x16x32_bf16(a0l, bh[1][ks], acc01, 0, 0, 0);
            acc01 = __builtin_amdgcn_mfma_f32_16x16x32_bf16(a0h, bl[1][ks], acc01, 0, 0, 0);
            acc10 = __builtin_amdgcn_mfma_f32_16x16x32_bf16(a1h, bh[0][ks], acc10, 0, 0, 0);
            acc10 = __builtin_amdgcn_mfma_f32_16x16x32_bf16(a1l, bh[0][ks], acc10, 0, 0, 0);
            acc10 = __builtin_amdgcn_mfma_f32_16x16x32_bf16(a1h, bl[0][ks], acc10, 0, 0, 0);
            acc11 = __builtin_amdgcn_mfma_f32_16x16x32_bf16(a1h, bh[1][ks], acc11, 0, 0, 0);
            acc11 = __builtin_amdgcn_mfma_f32_16x16x32_bf16(a1l, bh[1][ks], acc11, 0, 0, 0);
            acc11 = __builtin_amdgcn_mfma_f32_16x16x32_bf16(a1h, bl[1][ks], acc11, 0, 0, 0);
        }

        #pragma unroll
        for (int r = 0; r < 4; ++r) {
            const int row0 = kq * 4 + r;
            const int row1 = 16 + kq * 4 + r;
            const int d0 = sdst_sh[row0];
            const int d1 = sdst_sh[row1];
            const int n0 = wave * 32 + lr;
            const int n1 = wave * 32 + 16 + lr;
            atomicAdd(&accum[(size_t)d0 * ND + n0], acc00[r] + bias[0]);
            atomicAdd(&accum[(size_t)d0 * ND + n1], acc01[r] + bias[1]);
            atomicAdd(&accum[(size_t)d1 * ND + n0], acc10[r] + bias[0]);
            atomicAdd(&accum[(size_t)d1 * ND + n1], acc11[r] + bias[1]);
        }
        __syncthreads();
    }
}

// ---------------------------------------------------------------------------
// GRU kernel (MFMA, bf16x2): gi = a@W_ih, gh = h@W_hh (both 128->384),
// gates fused. Tile: 32 nodes x 384 cols; 4 waves, wave w owns cols
// [96w, 96w+96) = 6 n-tiles. B fragments from L2 (swizzled, coalesced).
// ---------------------------------------------------------------------------
__global__ __launch_bounds__(256, 2) void gru_mfma_kernel(
    const float* __restrict__ accum, const float* __restrict__ h_cur,
    const ushort_t* __restrict__ h_hi, const ushort_t* __restrict__ h_lo,
    const ushort_t* __restrict__ Bih_hi, const ushort_t* __restrict__ Bih_lo,
    const ushort_t* __restrict__ Bhh_hi, const ushort_t* __restrict__ Bhh_lo,
    const float* __restrict__ b_ih, const float* __restrict__ b_hh,
    float* __restrict__ h_out)
{
    // Phase 1: a/h staging (bf16 hi/lo, [32][136]); phase 2 reuses the same
    // LDS for gate pre-activations: grz [32][260] f32, gin/ghn [32][132] f32.
    __shared__ __align__(16) char smem[67072];
    ushort_t* sa_hi = (ushort_t*)smem;
    ushort_t* sa_lo = sa_hi + 32 * 136;
    ushort_t* sh_hi = sa_lo + 32 * 136;
    ushort_t* sh_lo = sh_hi + 32 * 136;
    float* grz = (float*)smem;          // [32][260]: cols 0-127 r-pre, 128-255 z-pre
    float* gin = grz + 32 * 260;        // [32][132]
    float* ghn = gin + 32 * 132;        // [32][132]

    const int t    = threadIdx.x;
    const int wave = t >> 6;
    const int lane = t & 63;
    const int kq   = lane >> 4;
    const int lr   = lane & 15;
    const int n0   = blockIdx.x * 32;

    // ---- stage: split accum rows; copy pre-split h rows ----
    {
        const int row = t >> 3, c8 = t & 7;
        const int n = min(n0 + row, N_NODES - 1);
        const float4* ap = (const float4*)(accum + (size_t)n * ND + c8 * 16);
        const float4 a0 = ap[0], a1 = ap[1], a2 = ap[2], a3 = ap[3];
        uint4 h0, h1, l0, l1;
        split2(a0.x, a0.y, h0.x, l0.x); split2(a0.z, a0.w, h0.y, l0.y);
        split2(a1.x, a1.y, h0.z, l0.z); split2(a1.z, a1.w, h0.w, l0.w);
        split2(a2.x, a2.y, h1.x, l1.x); split2(a2.z, a2.w, h1.y, l1.y);
        split2(a3.x, a3.y, h1.z, l1.z); split2(a3.z, a3.w, h1.w, l1.w);
        const int so = row * 136 + c8 * 16;
        *(uint4*)(sa_hi + so) = h0;  *(uint4*)(sa_hi + so + 8) = h1;
        *(uint4*)(sa_lo + so) = l0;  *(uint4*)(sa_lo + so + 8) = l1;
        const uint4* hp = (const uint4*)(h_hi + (size_t)n * ND + c8 * 16);
        *(uint4*)(sh_hi + so) = hp[0];  *(uint4*)(sh_hi + so + 8) = hp[1];
        const uint4* lp = (const uint4*)(h_lo + (size_t)n * ND + c8 * 16);
        *(uint4*)(sh_lo + so) = lp[0];  *(uint4*)(sh_lo + so + 8) = lp[1];
    }
    __syncthreads();

    f32x4 acc_i[2][6], acc_h[2][6];
    #pragma unroll
    for (int m = 0; m < 2; ++m)
        #pragma unroll
        for (int nt = 0; nt < 6; ++nt) {
            acc_i[m][nt] = (f32x4){0.f, 0.f, 0.f, 0.f};
            acc_h[m][nt] = (f32x4){0.f, 0.f, 0.f, 0.f};
        }

    #pragma unroll
    for (int ks = 0; ks < 4; ++ks) {
        bfrag afh[2], afl[2], hfh[2], hfl[2];
        #pragma unroll
        for (int m = 0; m < 2; ++m) {
            const int ao = (m * 16 + lr) * 136 + ks * 32 + kq * 8;
            afh[m] = *(const bfrag*)(sa_hi + ao);
            afl[m] = *(const bfrag*)(sa_lo + ao);
            hfh[m] = *(const bfrag*)(sh_hi + ao);
            hfl[m] = *(const bfrag*)(sh_lo + ao);
        }
        #pragma unroll
        for (int nt = 0; nt < 6; ++nt) {
            const int gnt = wave * 6 + nt;
            const int bo = (((gnt * 4 + ks) * 4 + kq) * 16 + lr) * 8;
            const bfrag bih_h = *(const bfrag*)(Bih_hi + bo);
            const bfrag bih_l = *(const bfrag*)(Bih_lo + bo);
            const bfrag bhh_h = *(const bfrag*)(Bhh_hi + bo);
            const bfrag bhh_l = *(const bfrag*)(Bhh_lo + bo);
            #pragma unroll
            for (int m = 0; m < 2; ++m) {
                acc_i[m][nt] = __builtin_amdgcn_mfma_f32_16x16x32_bf16(afh[m], bih_h, acc_i[m][nt], 0, 0, 0);
                acc_i[m][nt] = __builtin_amdgcn_mfma_f32_16x16x32_bf16(afl[m], bih_h, acc_i[m][nt], 0, 0, 0);
                acc_i[m][nt] = __builtin_amdgcn_mfma_f32_16x16x32_bf16(afh[m], bih_l, acc_i[m][nt], 0, 0, 0);
                acc_h[m][nt] = __builtin_amdgcn_mfma_f32_16x16x32_bf16(hfh[m], bhh_h, acc_h[m][nt], 0, 0, 0);
                acc_h[m][nt] = __builtin_amdgcn_mfma_f32_16x16x32_bf16(hfl[m], bhh_h, acc_h[m][nt], 0, 0, 0);
                acc_h[m][nt] = __builtin_amdgcn_mfma_f32_16x16x32_bf16(hfh[m], bhh_l, acc_h[m][nt], 0, 0, 0);
            }
        }
    }
    __syncthreads();   // all fragment reads done before LDS reuse

    // ---- write gate pre-activations (C/D: col = lane&15, row = kq*4+reg) ----
    #pragma unroll
    for (int nt = 0; nt < 6; ++nt) {
        const int gcol = wave * 96 + nt * 16 + lr;
        if (gcol < 256) {                      // r/z region: gi+gh fused
            const float bias = b_ih[gcol] + b_hh[gcol];
            #pragma unroll
            for (int m = 0; m < 2; ++m)
                #pragma unroll
                for (int r = 0; r < 4; ++r)
                    grz[(m * 16 + kq * 4 + r) * 260 + gcol] =
                        acc_i[m][nt][r] + acc_h[m][nt][r] + bias;
        } else {                               // n region: keep gi/gh separate
            const int cc = gcol - 256;
            const float bi = b_ih[gcol], bh2 = b_hh[gcol];
            #pragma unroll
            for (int m = 0; m < 2; ++m)
                #pragma unroll
                for (int r = 0; r < 4; ++r) {
                    const int rw = m * 16 + kq * 4 + r;
                    gin[rw * 132 + cc] = acc_i[m][nt][r] + bi;
                    ghn[rw * 132 + cc] = acc_h[m][nt][r] + bh2;
                }
        }
    }
    __syncthreads();

    // ---- gates elementwise ----
    for (int idx = t; idx < 32 * ND; idx += 256) {
        const int nl = idx >> 7, cc = idx & 127;
        const int n = n0 + nl;
        if (n < N_NODES) {
            const float rp  = grz[nl * 260 + cc];
            const float zp  = grz[nl * 260 + 128 + cc];
            const float inp = gin[nl * 132 + cc];
            const float hnp = ghn[nl * 132 + cc];
            const float r = 1.f / (1.f + expf(-rp));
            const float z = 1.f / (1.f + expf(-zp));
            const float nn = tanhf(inp + r * hnp);
            h_out[(size_t)n * ND + cc] =
                (1.f - z) * nn + z * h_cur[(size_t)n * ND + cc];
        }
    }
}

// ---------------------------------------------------------------------------
extern "C" void kernel_launch(void* const* d_in, const int* in_sizes, int n_in,
                              void* d_out, int out_size, void* d_ws, size_t ws_size,
                              hipStream_t stream)
{
    const float* hv   = (const float*)d_in[0];
    const float* he   = (const float*)d_in[1];
    const int*   src  = (const int*)d_in[2];
    const int*   dst  = (const int*)d_in[3];
    const float* Wmsg = (const float*)d_in[4];
    const float* bmsg = (const float*)d_in[5];
    const float* Wih  = (const float*)d_in[6];
    const float* Whh  = (const float*)d_in[7];
    const float* bih  = (const float*)d_in[8];
    const float* bhh  = (const float*)d_in[9];
    float* out = (float*)d_out;

    char* p = (char*)d_ws;
    float* accum = (float*)p;                 p += (size_t)N_NODES * ND * 4;   // 25.6 MB
    ushort_t* hv_hi = (ushort_t*)p;           p += (size_t)N_NODES * ND * 2;   // 12.8 MB
    ushort_t* hv_lo = (ushort_t*)p;           p += (size_t)N_NODES * ND * 2;
    ushort_t* Wt_hi = (ushort_t*)p;           p += (size_t)2 * AD * CAT * 2;
    ushort_t* Wt_lo = (ushort_t*)p;           p += (size_t)2 * AD * CAT * 2;
    ushort_t* Bih_hi = (ushort_t*)p;          p += (size_t)2 * G3 * ND * 2;
    ushort_t* Bih_lo = (ushort_t*)p;          p += (size_t)2 * G3 * ND * 2;
    ushort_t* Bhh_hi = (ushort_t*)p;          p += (size_t)2 * G3 * ND * 2;
    ushort_t* Bhh_lo = (ushort_t*)p;          p += (size_t)2 * G3 * ND * 2;

    const size_t accum_bytes = (size_t)N_NODES * ND * sizeof(float);

    convert_w_kernel<<<(2 * CAT * AD + 255) / 256, 256, 0, stream>>>(Wmsg, Wt_hi, Wt_lo);
    convert_gatew_kernel<<<768, 256, 0, stream>>>(Wih, Whh, Bih_hi, Bih_lo, Bhh_hi, Bhh_lo);

    const int gru_blocks = (N_NODES + 31) / 32;   // 1563

    for (int t = 0; t < 2; ++t) {
        const float* h_cur = (t == 0) ? hv : out;
        split_f32_kernel<<<(N_NODES * ND / 4 + 255) / 256, 256, 0, stream>>>(
            h_cur, hv_hi, hv_lo, N_NODES * ND / 4);
        hipMemsetAsync(accum, 0, accum_bytes, stream);
        edge_mfma_kernel<<<2048, 256, 0, stream>>>(
            hv_hi, hv_lo, he, src, dst,
            Wt_hi + (size_t)t * AD * CAT, Wt_lo + (size_t)t * AD * CAT,
            bmsg + (size_t)t * AD, accum);
        gru_mfma_kernel<<<gru_blocks, 256, 0, stream>>>(
            accum, h_cur, hv_hi, hv_lo,
            Bih_hi + (size_t)t * G3 * ND, Bih_lo + (size_t)t * G3 * ND,
            Bhh_hi + (size_t)t * G3 * ND, Bhh_lo + (size_t)t * G3 * ND,
            bih + (size_t)t * G3, bhh + (size_t)t * G3, out);
    }
}

// Round 5
// 935.356 us; speedup vs baseline: 3.3092x; 1.1384x over previous
//
#include <hip/hip_runtime.h>

#define N_NODES 50000
#define N_EDGES 800000
#define ND 128
#define ED 32
#define AD 128
#define CAT 288   // 2*ND + ED
#define G3 384    // 3*ND

#define MT 32         // edges per MFMA tile
#define XPAD 296      // LDS row stride (bf16 elems), 16B-aligned
#define KSTEPS 9      // 288 / 32
#define SCAN_BS 512

typedef unsigned short ushort_t;
typedef __attribute__((ext_vector_type(8))) short bfrag;   // 8 bf16 (4 VGPRs)
typedef __attribute__((ext_vector_type(4))) float f32x4;   // MFMA accumulator

__device__ __forceinline__ unsigned int f2bf(float f) {
    unsigned int u = __float_as_uint(f);
    return (u + 0x7FFFu + ((u >> 16) & 1u)) >> 16;   // RTNE to bf16
}
__device__ __forceinline__ void split2(float a, float b,
                                       unsigned int& hi, unsigned int& lo) {
    const unsigned int ha = f2bf(a), hb = f2bf(b);
    const float ra = a - __uint_as_float(ha << 16);
    const float rb = b - __uint_as_float(hb << 16);
    hi = ha | (hb << 16);
    lo = f2bf(ra) | (f2bf(rb) << 16);
}

// ========================= counting sort by dst ============================
__global__ __launch_bounds__(256) void hist_kernel(
    const int* __restrict__ dst, int* __restrict__ deg)
{
    const int e = blockIdx.x * 256 + threadIdx.x;
    if (e < N_EDGES) atomicAdd(&deg[dst[e]], 1);
}

__global__ __launch_bounds__(SCAN_BS) void scan_block_kernel(
    const int* __restrict__ in, int* __restrict__ out,
    int* __restrict__ bsum, int n)
{
    __shared__ int s[SCAN_BS];
    const int g = blockIdx.x * SCAN_BS + threadIdx.x;
    const int v = (g < n) ? in[g] : 0;
    s[threadIdx.x] = v;
    __syncthreads();
    for (int off = 1; off < SCAN_BS; off <<= 1) {
        const int x = (threadIdx.x >= off) ? s[threadIdx.x - off] : 0;
        __syncthreads();
        s[threadIdx.x] += x;
        __syncthreads();
    }
    if (g < n) out[g] = s[threadIdx.x] - v;   // exclusive
    if (threadIdx.x == SCAN_BS - 1) bsum[blockIdx.x] = s[threadIdx.x];
}

__global__ __launch_bounds__(128) void scan_sums_kernel(int* __restrict__ bsum, int nb)
{
    __shared__ int s[128];
    const int i = threadIdx.x;
    s[i] = (i < nb) ? bsum[i] : 0;
    __syncthreads();
    if (i == 0) {
        int acc = 0;
        for (int k = 0; k < nb; ++k) { const int t = s[k]; s[k] = acc; acc += t; }
    }
    __syncthreads();
    if (i < nb) bsum[i] = s[i];
}

__global__ __launch_bounds__(SCAN_BS) void scan_add_kernel(
    int* __restrict__ out, const int* __restrict__ bsum, int n)
{
    const int g = blockIdx.x * SCAN_BS + threadIdx.x;
    if (g < n) out[g] += bsum[blockIdx.x];
}

// cursor starts as the exclusive-scan array; destroyed by the fill.
__global__ __launch_bounds__(256) void fill_kernel(
    const int* __restrict__ dst, int* __restrict__ cursor, int* __restrict__ perm)
{
    const int e = blockIdx.x * 256 + threadIdx.x;
    if (e < N_EDGES) {
        const int p = atomicAdd(&cursor[dst[e]], 1);
        perm[p] = e;
    }
}

// ========================= precision-split helpers =========================
__global__ __launch_bounds__(256) void split_f32_kernel(
    const float* __restrict__ x, ushort_t* __restrict__ hi,
    ushort_t* __restrict__ lo, int n4)
{
    const int id = blockIdx.x * 256 + threadIdx.x;
    if (id >= n4) return;
    const float4 v = ((const float4*)x)[id];
    uint2 h, l;
    split2(v.x, v.y, h.x, l.x); split2(v.z, v.w, h.y, l.y);
    ((uint2*)hi)[id] = h; ((uint2*)lo)[id] = l;
}

__global__ __launch_bounds__(256) void convert_w_kernel(
    const float* __restrict__ W,
    ushort_t* __restrict__ Wt_hi, ushort_t* __restrict__ Wt_lo)
{
    const int id = blockIdx.x * 256 + threadIdx.x;   // 2*288*128 = 73728
    if (id >= 2 * CAT * AD) return;
    const int n = id & (AD - 1);
    const int k = (id >> 7) % CAT;
    const int t = id / (CAT * AD);
    const float w = W[(size_t)t * CAT * AD + (size_t)k * AD + n];
    const unsigned int hi = f2bf(w);
    const float r = w - __uint_as_float(hi << 16);
    const size_t o = (size_t)t * AD * CAT + (size_t)n * CAT + k;
    Wt_hi[o] = (ushort_t)hi;
    Wt_lo[o] = (ushort_t)f2bf(r);
}

__global__ __launch_bounds__(256) void convert_gatew_kernel(
    const float* __restrict__ W_ih, const float* __restrict__ W_hh,
    ushort_t* __restrict__ Bih_hi, ushort_t* __restrict__ Bih_lo,
    ushort_t* __restrict__ Bhh_hi, ushort_t* __restrict__ Bhh_lo)
{
    const int id = blockIdx.x * 256 + threadIdx.x;   // 196608
    if (id >= 196608) return;
    const int t   = id / 98304;
    const int rem = id % 98304;
    const int mat = rem / 49152;
    const int q   = rem % 49152;
    const int nt = q / 2048,  r1 = q % 2048;
    const int ks = r1 / 512,  r2 = r1 % 512;
    const int kq = r2 / 128,  r3 = r2 % 128;
    const int lr = r3 / 8,    j  = r3 % 8;
    const int n = nt * 16 + lr;
    const int k = ks * 32 + kq * 8 + j;
    const float* W = mat ? W_hh : W_ih;
    const float w = W[(size_t)t * ND * G3 + (size_t)k * G3 + n];
    const unsigned int hi = f2bf(w);
    const float res = w - __uint_as_float(hi << 16);
    const size_t o = (size_t)t * 49152 + q;
    if (mat) { Bhh_hi[o] = (ushort_t)hi; Bhh_lo[o] = (ushort_t)f2bf(res); }
    else     { Bih_hi[o] = (ushort_t)hi; Bih_lo[o] = (ushort_t)f2bf(res); }
}

// ---------------------------------------------------------------------------
// Edge kernel (MFMA, bf16x2, dst-sorted): processes edges in perm order so
// each 32-edge tile holds runs of equal dst. MFMA output round-trips through
// LDS (reusing the staging buffer) and is merged per dst-run -> ~1 atomic
// per (segment, col) instead of per (edge, col).
// ---------------------------------------------------------------------------
__global__ __launch_bounds__(256, 2) void edge_mfma_kernel(
    const ushort_t* __restrict__ hv_hi, const ushort_t* __restrict__ hv_lo,
    const float* __restrict__ he,
    const int* __restrict__ src, const int* __restrict__ dst,
    const int* __restrict__ perm,
    const ushort_t* __restrict__ Wt_hi, const ushort_t* __restrict__ Wt_lo,
    const float* __restrict__ b,
    float* __restrict__ accum)
{
    __shared__ __align__(16) char smem[2 * MT * XPAD * 2];   // 37888 B
    ushort_t* xh = (ushort_t*)smem;                // [MT][XPAD]
    ushort_t* xl = xh + MT * XPAD;                 // [MT][XPAD]
    float* pmsg = (float*)smem;                    // [MT][132] aliases xh (16896 B)
    __shared__ int sdst_sh[MT];

    const int t    = threadIdx.x;
    const int wave = t >> 6;
    const int lane = t & 63;
    const int kq   = lane >> 4;
    const int lr   = lane & 15;

    bfrag bh[2][KSTEPS], bl[2][KSTEPS];
    float bias[2];
    #pragma unroll
    for (int nt = 0; nt < 2; ++nt) {
        const int n = wave * 32 + nt * 16 + lr;
        bias[nt] = b[n];
        const ushort_t* ph = Wt_hi + (size_t)n * CAT + kq * 8;
        const ushort_t* pl = Wt_lo + (size_t)n * CAT + kq * 8;
        #pragma unroll
        for (int ks = 0; ks < KSTEPS; ++ks) {
            bh[nt][ks] = *(const bfrag*)(ph + ks * 32);
            bl[nt][ks] = *(const bfrag*)(pl + ks * 32);
        }
    }

    const int e = t >> 3, c = t & 7;
    const int ntiles = N_EDGES / MT;   // 25000

    for (int tile = blockIdx.x; tile < ntiles; tile += gridDim.x) {
        const int e0 = tile * MT;

        const int eid = perm[e0 + e];
        if (t < MT) sdst_sh[t] = dst[perm[e0 + t]];
        const int se = src[eid];
        const int de = dst[eid];

        // hv[src]: 16 bf16 hi + 16 lo (pure copies)
        {
            const uint4* ph = (const uint4*)(hv_hi + (size_t)se * ND + c * 16);
            const uint4* pl = (const uint4*)(hv_lo + (size_t)se * ND + c * 16);
            *(uint4*)&xh[e * XPAD + c * 16]     = ph[0];  *(uint4*)&xh[e * XPAD + c * 16 + 8] = ph[1];
            *(uint4*)&xl[e * XPAD + c * 16]     = pl[0];  *(uint4*)&xl[e * XPAD + c * 16 + 8] = pl[1];
        }
        // hv[dst] (sorted -> mostly L1-resident runs)
        {
            const uint4* ph = (const uint4*)(hv_hi + (size_t)de * ND + c * 16);
            const uint4* pl = (const uint4*)(hv_lo + (size_t)de * ND + c * 16);
            *(uint4*)&xh[e * XPAD + ND + c * 16]     = ph[0];  *(uint4*)&xh[e * XPAD + ND + c * 16 + 8] = ph[1];
            *(uint4*)&xl[e * XPAD + ND + c * 16]     = pl[0];  *(uint4*)&xl[e * XPAD + ND + c * 16 + 8] = pl[1];
        }
        // he: 4 floats, split in-kernel
        {
            const float4 h4 = *(const float4*)(he + (size_t)eid * ED + c * 4);
            uint2 h0, l0;
            split2(h4.x, h4.y, h0.x, l0.x); split2(h4.z, h4.w, h0.y, l0.y);
            *(uint2*)&xh[e * XPAD + 2 * ND + c * 4] = h0;
            *(uint2*)&xl[e * XPAD + 2 * ND + c * 4] = l0;
        }
        __syncthreads();

        f32x4 acc00 = {0.f,0.f,0.f,0.f}, acc01 = {0.f,0.f,0.f,0.f};
        f32x4 acc10 = {0.f,0.f,0.f,0.f}, acc11 = {0.f,0.f,0.f,0.f};
        #pragma unroll
        for (int ks = 0; ks < KSTEPS; ++ks) {
            const int ko = ks * 32 + kq * 8;
            const bfrag a0h = *(const bfrag*)&xh[lr * XPAD + ko];
            const bfrag a0l = *(const bfrag*)&xl[lr * XPAD + ko];
            const bfrag a1h = *(const bfrag*)&xh[(16 + lr) * XPAD + ko];
            const bfrag a1l = *(const bfrag*)&xl[(16 + lr) * XPAD + ko];
            acc00 = __builtin_amdgcn_mfma_f32_16x16x32_bf16(a0h, bh[0][ks], acc00, 0, 0, 0);
            acc00 = __builtin_amdgcn_mfma_f32_16x16x32_bf16(a0l, bh[0][ks], acc00, 0, 0, 0);
            acc00 = __builtin_amdgcn_mfma_f32_16x16x32_bf16(a0h, bl[0][ks], acc00, 0, 0, 0);
            acc01 = __builtin_amdgcn_mfma_f32_16x16x32_bf16(a0h, bh[1][ks], acc01, 0, 0, 0);
            acc01 = __builtin_amdgcn_mfma_f32_16x16x32_bf16(a0l, bh[1][ks], acc01, 0, 0, 0);
            acc01 = __builtin_amdgcn_mfma_f32_16x16x32_bf16(a0h, bl[1][ks], acc01, 0, 0, 0);
            acc10 = __builtin_amdgcn_mfma_f32_16x16x32_bf16(a1h, bh[0][ks], acc10, 0, 0, 0);
            acc10 = __builtin_amdgcn_mfma_f32_16x16x32_bf16(a1l, bh[0][ks], acc10, 0, 0, 0);
            acc10 = __builtin_amdgcn_mfma_f32_16x16x32_bf16(a1h, bl[0][ks], acc10, 0, 0, 0);
            acc11 = __builtin_amdgcn_mfma_f32_16x16x32_bf16(a1h, bh[1][ks], acc11, 0, 0, 0);
            acc11 = __builtin_amdgcn_mfma_f32_16x16x32_bf16(a1l, bh[1][ks], acc11, 0, 0, 0);
            acc11 = __builtin_amdgcn_mfma_f32_16x16x32_bf16(a1h, bl[1][ks], acc11, 0, 0, 0);
        }
        __syncthreads();   // all xh/xl fragment reads done before LDS reuse

        // C/D layout: col = lane&15, row = kq*4 + reg. Write msg tile to LDS.
        #pragma unroll
        for (int r = 0; r < 4; ++r) {
            const int row0 = kq * 4 + r;
            const int row1 = 16 + kq * 4 + r;
            const int n0 = wave * 32 + lr;
            const int n1 = wave * 32 + 16 + lr;
            pmsg[row0 * 132 + n0] = acc00[r] + bias[0];
            pmsg[row0 * 132 + n1] = acc01[r] + bias[1];
            pmsg[row1 * 132 + n0] = acc10[r] + bias[0];
            pmsg[row1 * 132 + n1] = acc11[r] + bias[1];
        }
        __syncthreads();

        // Merge runs of equal dst: one atomic per (run, col).
        if (t < ND) {
            float run = 0.f;
            int prev = sdst_sh[0];
            #pragma unroll 4
            for (int row = 0; row < MT; ++row) {
                const int d = sdst_sh[row];
                const float v = pmsg[row * 132 + t];
                if (d != prev) {
                    atomicAdd(&accum[(size_t)prev * ND + t], run);
                    run = 0.f; prev = d;
                }
                run += v;
            }
            atomicAdd(&accum[(size_t)prev * ND + t], run);
        }
        __syncthreads();
    }
}

// ---------------------------------------------------------------------------
// GRU kernel (MFMA, bf16x2) — unchanged from R4.
// ---------------------------------------------------------------------------
__global__ __launch_bounds__(256, 2) void gru_mfma_kernel(
    const float* __restrict__ accum, const float* __restrict__ h_cur,
    const ushort_t* __restrict__ h_hi, const ushort_t* __restrict__ h_lo,
    const ushort_t* __restrict__ Bih_hi, const ushort_t* __restrict__ Bih_lo,
    const ushort_t* __restrict__ Bhh_hi, const ushort_t* __restrict__ Bhh_lo,
    const float* __restrict__ b_ih, const float* __restrict__ b_hh,
    float* __restrict__ h_out)
{
    __shared__ __align__(16) char smem[67072];
    ushort_t* sa_hi = (ushort_t*)smem;
    ushort_t* sa_lo = sa_hi + 32 * 136;
    ushort_t* sh_hi = sa_lo + 32 * 136;
    ushort_t* sh_lo = sh_hi + 32 * 136;
    float* grz = (float*)smem;          // [32][260]
    float* gin = grz + 32 * 260;        // [32][132]
    float* ghn = gin + 32 * 132;        // [32][132]

    const int t    = threadIdx.x;
    const int wave = t >> 6;
    const int lane = t & 63;
    const int kq   = lane >> 4;
    const int lr   = lane & 15;
    const int n0   = blockIdx.x * 32;

    {
        const int row = t >> 3, c8 = t & 7;
        const int n = min(n0 + row, N_NODES - 1);
        const float4* ap = (const float4*)(accum + (size_t)n * ND + c8 * 16);
        const float4 a0 = ap[0], a1 = ap[1], a2 = ap[2], a3 = ap[3];
        uint4 h0, h1, l0, l1;
        split2(a0.x, a0.y, h0.x, l0.x); split2(a0.z, a0.w, h0.y, l0.y);
        split2(a1.x, a1.y, h0.z, l0.z); split2(a1.z, a1.w, h0.w, l0.w);
        split2(a2.x, a2.y, h1.x, l1.x); split2(a2.z, a2.w, h1.y, l1.y);
        split2(a3.x, a3.y, h1.z, l1.z); split2(a3.z, a3.w, h1.w, l1.w);
        const int so = row * 136 + c8 * 16;
        *(uint4*)(sa_hi + so) = h0;  *(uint4*)(sa_hi + so + 8) = h1;
        *(uint4*)(sa_lo + so) = l0;  *(uint4*)(sa_lo + so + 8) = l1;
        const uint4* hp = (const uint4*)(h_hi + (size_t)n * ND + c8 * 16);
        *(uint4*)(sh_hi + so) = hp[0];  *(uint4*)(sh_hi + so + 8) = hp[1];
        const uint4* lp = (const uint4*)(h_lo + (size_t)n * ND + c8 * 16);
        *(uint4*)(sh_lo + so) = lp[0];  *(uint4*)(sh_lo + so + 8) = lp[1];
    }
    __syncthreads();

    f32x4 acc_i[2][6], acc_h[2][6];
    #pragma unroll
    for (int m = 0; m < 2; ++m)
        #pragma unroll
        for (int nt = 0; nt < 6; ++nt) {
            acc_i[m][nt] = (f32x4){0.f, 0.f, 0.f, 0.f};
            acc_h[m][nt] = (f32x4){0.f, 0.f, 0.f, 0.f};
        }

    #pragma unroll
    for (int ks = 0; ks < 4; ++ks) {
        bfrag afh[2], afl[2], hfh[2], hfl[2];
        #pragma unroll
        for (int m = 0; m < 2; ++m) {
            const int ao = (m * 16 + lr) * 136 + ks * 32 + kq * 8;
            afh[m] = *(const bfrag*)(sa_hi + ao);
            afl[m] = *(const bfrag*)(sa_lo + ao);
            hfh[m] = *(const bfrag*)(sh_hi + ao);
            hfl[m] = *(const bfrag*)(sh_lo + ao);
        }
        #pragma unroll
        for (int nt = 0; nt < 6; ++nt) {
            const int gnt = wave * 6 + nt;
            const int bo = (((gnt * 4 + ks) * 4 + kq) * 16 + lr) * 8;
            const bfrag bih_h = *(const bfrag*)(Bih_hi + bo);
            const bfrag bih_l = *(const bfrag*)(Bih_lo + bo);
            const bfrag bhh_h = *(const bfrag*)(Bhh_hi + bo);
            const bfrag bhh_l = *(const bfrag*)(Bhh_lo + bo);
            #pragma unroll
            for (int m = 0; m < 2; ++m) {
                acc_i[m][nt] = __builtin_amdgcn_mfma_f32_16x16x32_bf16(afh[m], bih_h, acc_i[m][nt], 0, 0, 0);
                acc_i[m][nt] = __builtin_amdgcn_mfma_f32_16x16x32_bf16(afl[m], bih_h, acc_i[m][nt], 0, 0, 0);
                acc_i[m][nt] = __builtin_amdgcn_mfma_f32_16x16x32_bf16(afh[m], bih_l, acc_i[m][nt], 0, 0, 0);
                acc_h[m][nt] = __builtin_amdgcn_mfma_f32_16x16x32_bf16(hfh[m], bhh_h, acc_h[m][nt], 0, 0, 0);
                acc_h[m][nt] = __builtin_amdgcn_mfma_f32_16x16x32_bf16(hfl[m], bhh_h, acc_h[m][nt], 0, 0, 0);
                acc_h[m][nt] = __builtin_amdgcn_mfma_f32_16x16x32_bf16(hfh[m], bhh_l, acc_h[m][nt], 0, 0, 0);
            }
        }
    }
    __syncthreads();

    #pragma unroll
    for (int nt = 0; nt < 6; ++nt) {
        const int gcol = wave * 96 + nt * 16 + lr;
        if (gcol < 256) {
            const float bias = b_ih[gcol] + b_hh[gcol];
            #pragma unroll
            for (int m = 0; m < 2; ++m)
                #pragma unroll
                for (int r = 0; r < 4; ++r)
                    grz[(m * 16 + kq * 4 + r) * 260 + gcol] =
                        acc_i[m][nt][r] + acc_h[m][nt][r] + bias;
        } else {
            const int cc = gcol - 256;
            const float bi = b_ih[gcol], bh2 = b_hh[gcol];
            #pragma unroll
            for (int m = 0; m < 2; ++m)
                #pragma unroll
                for (int r = 0; r < 4; ++r) {
                    const int rw = m * 16 + kq * 4 + r;
                    gin[rw * 132 + cc] = acc_i[m][nt][r] + bi;
                    ghn[rw * 132 + cc] = acc_h[m][nt][r] + bh2;
                }
        }
    }
    __syncthreads();

    for (int idx = t; idx < 32 * ND; idx += 256) {
        const int nl = idx >> 7, cc = idx & 127;
        const int n = n0 + nl;
        if (n < N_NODES) {
            const float rp  = grz[nl * 260 + cc];
            const float zp  = grz[nl * 260 + 128 + cc];
            const float inp = gin[nl * 132 + cc];
            const float hnp = ghn[nl * 132 + cc];
            const float r = 1.f / (1.f + expf(-rp));
            const float z = 1.f / (1.f + expf(-zp));
            const float nn = tanhf(inp + r * hnp);
            h_out[(size_t)n * ND + cc] =
                (1.f - z) * nn + z * h_cur[(size_t)n * ND + cc];
        }
    }
}

// ---------------------------------------------------------------------------
extern "C" void kernel_launch(void* const* d_in, const int* in_sizes, int n_in,
                              void* d_out, int out_size, void* d_ws, size_t ws_size,
                              hipStream_t stream)
{
    const float* hv   = (const float*)d_in[0];
    const float* he   = (const float*)d_in[1];
    const int*   src  = (const int*)d_in[2];
    const int*   dst  = (const int*)d_in[3];
    const float* Wmsg = (const float*)d_in[4];
    const float* bmsg = (const float*)d_in[5];
    const float* Wih  = (const float*)d_in[6];
    const float* Whh  = (const float*)d_in[7];
    const float* bih  = (const float*)d_in[8];
    const float* bhh  = (const float*)d_in[9];
    float* out = (float*)d_out;

    const int nscan = ((N_NODES + SCAN_BS - 1) / SCAN_BS) * SCAN_BS;  // 50176
    const int nblk  = nscan / SCAN_BS;                                // 98

    char* p = (char*)d_ws;
    float* accum = (float*)p;                 p += (size_t)N_NODES * ND * 4;   // 25.6 MB
    ushort_t* hv_hi = (ushort_t*)p;           p += (size_t)N_NODES * ND * 2;
    ushort_t* hv_lo = (ushort_t*)p;           p += (size_t)N_NODES * ND * 2;
    ushort_t* Wt_hi = (ushort_t*)p;           p += (size_t)2 * AD * CAT * 2;
    ushort_t* Wt_lo = (ushort_t*)p;           p += (size_t)2 * AD * CAT * 2;
    ushort_t* Bih_hi = (ushort_t*)p;          p += (size_t)2 * G3 * ND * 2;
    ushort_t* Bih_lo = (ushort_t*)p;          p += (size_t)2 * G3 * ND * 2;
    ushort_t* Bhh_hi = (ushort_t*)p;          p += (size_t)2 * G3 * ND * 2;
    ushort_t* Bhh_lo = (ushort_t*)p;          p += (size_t)2 * G3 * ND * 2;
    int* deg    = (int*)p;                    p += (size_t)nscan * 4;
    int* cursor = (int*)p;                    p += (size_t)nscan * 4;
    int* bsum   = (int*)p;                    p += 128 * 4;
    int* perm   = (int*)p;                    p += (size_t)N_EDGES * 4;

    const size_t accum_bytes = (size_t)N_NODES * ND * sizeof(float);

    // ---- one-time per launch: weights + counting sort of edges by dst ----
    convert_w_kernel<<<(2 * CAT * AD + 255) / 256, 256, 0, stream>>>(Wmsg, Wt_hi, Wt_lo);
    convert_gatew_kernel<<<768, 256, 0, stream>>>(Wih, Whh, Bih_hi, Bih_lo, Bhh_hi, Bhh_lo);

    hipMemsetAsync(deg, 0, (size_t)nscan * 4, stream);
    hist_kernel<<<(N_EDGES + 255) / 256, 256, 0, stream>>>(dst, deg);
    scan_block_kernel<<<nblk, SCAN_BS, 0, stream>>>(deg, cursor, bsum, nscan);
    scan_sums_kernel<<<1, 128, 0, stream>>>(bsum, nblk);
    scan_add_kernel<<<nblk, SCAN_BS, 0, stream>>>(cursor, bsum, nscan);
    fill_kernel<<<(N_EDGES + 255) / 256, 256, 0, stream>>>(dst, cursor, perm);

    const int gru_blocks = (N_NODES + 31) / 32;   // 1563

    for (int t = 0; t < 2; ++t) {
        const float* h_cur = (t == 0) ? hv : out;
        split_f32_kernel<<<(N_NODES * ND / 4 + 255) / 256, 256, 0, stream>>>(
            h_cur, hv_hi, hv_lo, N_NODES * ND / 4);
        hipMemsetAsync(accum, 0, accum_bytes, stream);
        edge_mfma_kernel<<<2048, 256, 0, stream>>>(
            hv_hi, hv_lo, he, src, dst, perm,
            Wt_hi + (size_t)t * AD * CAT, Wt_lo + (size_t)t * AD * CAT,
            bmsg + (size_t)t * AD, accum);
        gru_mfma_kernel<<<gru_blocks, 256, 0, stream>>>(
            accum, h_cur, hv_hi, hv_lo,
            Bih_hi + (size_t)t * G3 * ND, Bih_lo + (size_t)t * G3 * ND,
            Bhh_hi + (size_t)t * G3 * ND, Bhh_lo + (size_t)t * G3 * ND,
            bih + (size_t)t * G3, bhh + (size_t)t * G3, out);
    }
}

// Round 6
// 642.166 us; speedup vs baseline: 4.8200x; 1.4566x over previous
//
#include <hip/hip_runtime.h>

#define N_NODES 50000
#define N_EDGES 800000
#define ND 128
#define ED 32
#define AD 128
#define CAT 288   // 2*ND + ED
#define G3 384    // 3*ND

#define XPAD 296      // LDS row stride (bf16 elems), 16B-aligned
#define KSTEPS 9      // 288 / 32
#define SCAN_BS 512

typedef unsigned short ushort_t;
typedef __attribute__((ext_vector_type(8))) short bfrag;   // 8 bf16 (4 VGPRs)
typedef __attribute__((ext_vector_type(4))) float f32x4;   // MFMA accumulator

__device__ __forceinline__ unsigned int f2bf(float f) {
    unsigned int u = __float_as_uint(f);
    return (u + 0x7FFFu + ((u >> 16) & 1u)) >> 16;   // RTNE to bf16
}
__device__ __forceinline__ void split2(float a, float b,
                                       unsigned int& hi, unsigned int& lo) {
    const unsigned int ha = f2bf(a), hb = f2bf(b);
    const float ra = a - __uint_as_float(ha << 16);
    const float rb = b - __uint_as_float(hb << 16);
    hi = ha | (hb << 16);
    lo = f2bf(ra) | (f2bf(rb) << 16);
}

// ========================= counting sort by dst ============================
__global__ __launch_bounds__(256) void hist_kernel(
    const int* __restrict__ dst, int* __restrict__ deg)
{
    const int e = blockIdx.x * 256 + threadIdx.x;
    if (e < N_EDGES) atomicAdd(&deg[dst[e]], 1);
}

__global__ __launch_bounds__(SCAN_BS) void scan_block_kernel(
    const int* __restrict__ in, int* __restrict__ out,
    int* __restrict__ bsum, int n)
{
    __shared__ int s[SCAN_BS];
    const int g = blockIdx.x * SCAN_BS + threadIdx.x;
    const int v = (g < n) ? in[g] : 0;
    s[threadIdx.x] = v;
    __syncthreads();
    for (int off = 1; off < SCAN_BS; off <<= 1) {
        const int x = (threadIdx.x >= off) ? s[threadIdx.x - off] : 0;
        __syncthreads();
        s[threadIdx.x] += x;
        __syncthreads();
    }
    if (g < n) out[g] = s[threadIdx.x] - v;   // exclusive
    if (threadIdx.x == SCAN_BS - 1) bsum[blockIdx.x] = s[threadIdx.x];
}

__global__ __launch_bounds__(128) void scan_sums_kernel(int* __restrict__ bsum, int nb)
{
    __shared__ int s[128];
    const int i = threadIdx.x;
    s[i] = (i < nb) ? bsum[i] : 0;
    __syncthreads();
    if (i == 0) {
        int acc = 0;
        for (int k = 0; k < nb; ++k) { const int t = s[k]; s[k] = acc; acc += t; }
    }
    __syncthreads();
    if (i < nb) bsum[i] = s[i];
}

__global__ __launch_bounds__(SCAN_BS) void scan_add_kernel(
    int* __restrict__ out, const int* __restrict__ bsum, int n)
{
    const int g = blockIdx.x * SCAN_BS + threadIdx.x;
    if (g < n) out[g] += bsum[blockIdx.x];
}

// cursor starts as a copy of rowptr; destroyed by the fill.
__global__ __launch_bounds__(256) void fill_kernel(
    const int* __restrict__ dst, const int* __restrict__ src,
    int* __restrict__ cursor, int* __restrict__ perm,
    int* __restrict__ src_sorted)
{
    const int e = blockIdx.x * 256 + threadIdx.x;
    if (e < N_EDGES) {
        const int p = atomicAdd(&cursor[dst[e]], 1);
        perm[p] = e;
        src_sorted[p] = src[e];
    }
}

// E[v] = sum of he rows over in-edges of v (round-invariant, once per launch).
__global__ __launch_bounds__(256) void esum_kernel(
    const float* __restrict__ he, const int* __restrict__ perm,
    const int* __restrict__ rowptr, float* __restrict__ E)
{
    const int id = blockIdx.x * 256 + threadIdx.x;   // N_NODES*32 ids
    if (id >= N_NODES * ED) return;
    const int v = id >> 5, c = id & 31;
    const int r0 = rowptr[v], r1 = rowptr[v + 1];
    float s = 0.f;
    for (int i = r0; i < r1; ++i)
        s += he[(size_t)perm[i] * ED + c];
    E[(size_t)v * ED + c] = s;
}

// ========================= weight converts (once) ==========================
__global__ __launch_bounds__(256) void convert_w_kernel(
    const float* __restrict__ W,
    ushort_t* __restrict__ Wt_hi, ushort_t* __restrict__ Wt_lo)
{
    const int id = blockIdx.x * 256 + threadIdx.x;   // 2*288*128 = 73728
    if (id >= 2 * CAT * AD) return;
    const int n = id & (AD - 1);
    const int k = (id >> 7) % CAT;
    const int t = id / (CAT * AD);
    const float w = W[(size_t)t * CAT * AD + (size_t)k * AD + n];
    const unsigned int hi = f2bf(w);
    const float r = w - __uint_as_float(hi << 16);
    const size_t o = (size_t)t * AD * CAT + (size_t)n * CAT + k;
    Wt_hi[o] = (ushort_t)hi;
    Wt_lo[o] = (ushort_t)f2bf(r);
}

__global__ __launch_bounds__(256) void convert_gatew_kernel(
    const float* __restrict__ W_ih, const float* __restrict__ W_hh,
    ushort_t* __restrict__ Bih_hi, ushort_t* __restrict__ Bih_lo,
    ushort_t* __restrict__ Bhh_hi, ushort_t* __restrict__ Bhh_lo)
{
    const int id = blockIdx.x * 256 + threadIdx.x;   // 196608
    if (id >= 196608) return;
    const int t   = id / 98304;
    const int rem = id % 98304;
    const int mat = rem / 49152;
    const int q   = rem % 49152;
    const int nt = q / 2048,  r1 = q % 2048;
    const int ks = r1 / 512,  r2 = r1 % 512;
    const int kq = r2 / 128,  r3 = r2 % 128;
    const int lr = r3 / 8,    j  = r3 % 8;
    const int n = nt * 16 + lr;
    const int k = ks * 32 + kq * 8 + j;
    const float* W = mat ? W_hh : W_ih;
    const float w = W[(size_t)t * ND * G3 + (size_t)k * G3 + n];
    const unsigned int hi = f2bf(w);
    const float res = w - __uint_as_float(hi << 16);
    const size_t o = (size_t)t * 49152 + q;
    if (mat) { Bhh_hi[o] = (ushort_t)hi; Bhh_lo[o] = (ushort_t)f2bf(res); }
    else     { Bih_hi[o] = (ushort_t)hi; Bih_lo[o] = (ushort_t)f2bf(res); }
}

// ---------------------------------------------------------------------------
// Aggregation: S[v] = sum over in-edges of hv[src_e] (fp32), output pre-split
// to bf16 hi/lo. One wave per node; lane holds 2 cols (float2); 4x unrolled
// independent gathers for ILP.
// ---------------------------------------------------------------------------
__global__ __launch_bounds__(256) void agg_kernel(
    const float* __restrict__ hv, const int* __restrict__ src_sorted,
    const int* __restrict__ rowptr,
    ushort_t* __restrict__ S_hi, ushort_t* __restrict__ S_lo)
{
    const int v = blockIdx.x * 4 + (threadIdx.x >> 6);
    if (v >= N_NODES) return;
    const int lane = threadIdx.x & 63;
    const int r0 = rowptr[v], r1 = rowptr[v + 1];
    const float2* hv2 = (const float2*)hv;
    float sx = 0.f, sy = 0.f;
    int i = r0;
    for (; i + 4 <= r1; i += 4) {
        const int s0 = src_sorted[i],     s1 = src_sorted[i + 1];
        const int s2 = src_sorted[i + 2], s3 = src_sorted[i + 3];
        const float2 a = hv2[(size_t)s0 * 64 + lane];
        const float2 b = hv2[(size_t)s1 * 64 + lane];
        const float2 c = hv2[(size_t)s2 * 64 + lane];
        const float2 d = hv2[(size_t)s3 * 64 + lane];
        sx += (a.x + b.x) + (c.x + d.x);
        sy += (a.y + b.y) + (c.y + d.y);
    }
    for (; i < r1; ++i) {
        const float2 a = hv2[(size_t)src_sorted[i] * 64 + lane];
        sx += a.x; sy += a.y;
    }
    unsigned int h, l;
    split2(sx, sy, h, l);
    ((unsigned int*)S_hi)[(size_t)v * 64 + lane] = h;
    ((unsigned int*)S_lo)[(size_t)v * 64 + lane] = l;
}

// ---------------------------------------------------------------------------
// Msg kernel (MFMA, bf16x2): a = [S, deg*h, E] @ Wmsg + deg*b.
// One 32-node x 128-col tile per block; 4 waves, wave w owns cols [32w,32w+32).
// ---------------------------------------------------------------------------
__global__ __launch_bounds__(256, 2) void msg_mfma_kernel(
    const ushort_t* __restrict__ S_hi, const ushort_t* __restrict__ S_lo,
    const float* __restrict__ h_cur, const float* __restrict__ E,
    const int* __restrict__ rowptr,
    const ushort_t* __restrict__ Wt_hi, const ushort_t* __restrict__ Wt_lo,
    const float* __restrict__ b,
    float* __restrict__ a_out)
{
    __shared__ ushort_t xh[32][XPAD];
    __shared__ ushort_t xl[32][XPAD];
    __shared__ float sdeg[32];

    const int t    = threadIdx.x;
    const int wave = t >> 6;
    const int lane = t & 63;
    const int kq   = lane >> 4;
    const int lr   = lane & 15;
    const int n0   = blockIdx.x * 32;

    // B fragments: 2 n-tiles x 9 k-steps, hi+lo.
    bfrag bh[2][KSTEPS], bl[2][KSTEPS];
    float bias[2];
    #pragma unroll
    for (int nt = 0; nt < 2; ++nt) {
        const int n = wave * 32 + nt * 16 + lr;
        bias[nt] = b[n];
        const ushort_t* ph = Wt_hi + (size_t)n * CAT + kq * 8;
        const ushort_t* pl = Wt_lo + (size_t)n * CAT + kq * 8;
        #pragma unroll
        for (int ks = 0; ks < KSTEPS; ++ks) {
            bh[nt][ks] = *(const bfrag*)(ph + ks * 32);
            bl[nt][ks] = *(const bfrag*)(pl + ks * 32);
        }
    }

    // ---- stage X = [S | deg*h | E] ----
    {
        const int row = t >> 3, c8 = t & 7;
        const int n = min(n0 + row, N_NODES - 1);
        if (t < 32) {
            const int nn = min(n0 + t, N_NODES - 1);
            sdeg[t] = (float)(rowptr[nn + 1] - rowptr[nn]);
        }
        // S: pre-split copies
        {
            const uint4* ph = (const uint4*)(S_hi + (size_t)n * ND + c8 * 16);
            const uint4* pl = (const uint4*)(S_lo + (size_t)n * ND + c8 * 16);
            *(uint4*)&xh[row][c8 * 16]     = ph[0];  *(uint4*)&xh[row][c8 * 16 + 8] = ph[1];
            *(uint4*)&xl[row][c8 * 16]     = pl[0];  *(uint4*)&xl[row][c8 * 16 + 8] = pl[1];
        }
        // deg*h: fp32 load, scale, split
        {
            const float degf = (float)(rowptr[n + 1] - rowptr[n]);
            const float4* hp = (const float4*)(h_cur + (size_t)n * ND + c8 * 16);
            float4 v0 = hp[0], v1 = hp[1], v2 = hp[2], v3 = hp[3];
            v0.x *= degf; v0.y *= degf; v0.z *= degf; v0.w *= degf;
            v1.x *= degf; v1.y *= degf; v1.z *= degf; v1.w *= degf;
            v2.x *= degf; v2.y *= degf; v2.z *= degf; v2.w *= degf;
            v3.x *= degf; v3.y *= degf; v3.z *= degf; v3.w *= degf;
            uint4 h0, h1, l0, l1;
            split2(v0.x, v0.y, h0.x, l0.x); split2(v0.z, v0.w, h0.y, l0.y);
            split2(v1.x, v1.y, h0.z, l0.z); split2(v1.z, v1.w, h0.w, l0.w);
            split2(v2.x, v2.y, h1.x, l1.x); split2(v2.z, v2.w, h1.y, l1.y);
            split2(v3.x, v3.y, h1.z, l1.z); split2(v3.z, v3.w, h1.w, l1.w);
            *(uint4*)&xh[row][ND + c8 * 16]     = h0;  *(uint4*)&xh[row][ND + c8 * 16 + 8] = h1;
            *(uint4*)&xl[row][ND + c8 * 16]     = l0;  *(uint4*)&xl[row][ND + c8 * 16 + 8] = l1;
        }
        // E: 4 floats
        {
            const float4 e4 = *(const float4*)(E + (size_t)n * ED + c8 * 4);
            uint2 h0, l0;
            split2(e4.x, e4.y, h0.x, l0.x); split2(e4.z, e4.w, h0.y, l0.y);
            *(uint2*)&xh[row][2 * ND + c8 * 4] = h0;
            *(uint2*)&xl[row][2 * ND + c8 * 4] = l0;
        }
    }
    __syncthreads();

    f32x4 acc00 = {0.f,0.f,0.f,0.f}, acc01 = {0.f,0.f,0.f,0.f};
    f32x4 acc10 = {0.f,0.f,0.f,0.f}, acc11 = {0.f,0.f,0.f,0.f};
    #pragma unroll
    for (int ks = 0; ks < KSTEPS; ++ks) {
        const int ko = ks * 32 + kq * 8;
        const bfrag a0h = *(const bfrag*)&xh[lr][ko];
        const bfrag a0l = *(const bfrag*)&xl[lr][ko];
        const bfrag a1h = *(const bfrag*)&xh[16 + lr][ko];
        const bfrag a1l = *(const bfrag*)&xl[16 + lr][ko];
        acc00 = __builtin_amdgcn_mfma_f32_16x16x32_bf16(a0h, bh[0][ks], acc00, 0, 0, 0);
        acc00 = __builtin_amdgcn_mfma_f32_16x16x32_bf16(a0l, bh[0][ks], acc00, 0, 0, 0);
        acc00 = __builtin_amdgcn_mfma_f32_16x16x32_bf16(a0h, bl[0][ks], acc00, 0, 0, 0);
        acc01 = __builtin_amdgcn_mfma_f32_16x16x32_bf16(a0h, bh[1][ks], acc01, 0, 0, 0);
        acc01 = __builtin_amdgcn_mfma_f32_16x16x32_bf16(a0l, bh[1][ks], acc01, 0, 0, 0);
        acc01 = __builtin_amdgcn_mfma_f32_16x16x32_bf16(a0h, bl[1][ks], acc01, 0, 0, 0);
        acc10 = __builtin_amdgcn_mfma_f32_16x16x32_bf16(a1h, bh[0][ks], acc10, 0, 0, 0);
        acc10 = __builtin_amdgcn_mfma_f32_16x16x32_bf16(a1l, bh[0][ks], acc10, 0, 0, 0);
        acc10 = __builtin_amdgcn_mfma_f32_16x16x32_bf16(a1h, bl[0][ks], acc10, 0, 0, 0);
        acc11 = __builtin_amdgcn_mfma_f32_16x16x32_bf16(a1h, bh[1][ks], acc11, 0, 0, 0);
        acc11 = __builtin_amdgcn_mfma_f32_16x16x32_bf16(a1l, bh[1][ks], acc11, 0, 0, 0);
        acc11 = __builtin_amdgcn_mfma_f32_16x16x32_bf16(a1h, bl[1][ks], acc11, 0, 0, 0);
    }

    // Epilogue: C/D col = lane&15, row = kq*4 + reg. a += deg*bias.
    #pragma unroll
    for (int r = 0; r < 4; ++r) {
        const int row0 = kq * 4 + r;
        const int row1 = 16 + kq * 4 + r;
        const int nA = n0 + row0, nB = n0 + row1;
        const int c0 = wave * 32 + lr, c1 = wave * 32 + 16 + lr;
        if (nA < N_NODES) {
            a_out[(size_t)nA * ND + c0] = acc00[r] + sdeg[row0] * bias[0];
            a_out[(size_t)nA * ND + c1] = acc01[r] + sdeg[row0] * bias[1];
        }
        if (nB < N_NODES) {
            a_out[(size_t)nB * ND + c0] = acc10[r] + sdeg[row1] * bias[0];
            a_out[(size_t)nB * ND + c1] = acc11[r] + sdeg[row1] * bias[1];
        }
    }
}

// ---------------------------------------------------------------------------
// GRU kernel (MFMA, bf16x2): h split in-kernel now (no pre-split pass).
// ---------------------------------------------------------------------------
__global__ __launch_bounds__(256, 2) void gru_mfma_kernel(
    const float* __restrict__ accum, const float* __restrict__ h_cur,
    const ushort_t* __restrict__ Bih_hi, const ushort_t* __restrict__ Bih_lo,
    const ushort_t* __restrict__ Bhh_hi, const ushort_t* __restrict__ Bhh_lo,
    const float* __restrict__ b_ih, const float* __restrict__ b_hh,
    float* __restrict__ h_out)
{
    __shared__ __align__(16) char smem[67072];
    ushort_t* sa_hi = (ushort_t*)smem;
    ushort_t* sa_lo = sa_hi + 32 * 136;
    ushort_t* sh_hi = sa_lo + 32 * 136;
    ushort_t* sh_lo = sh_hi + 32 * 136;
    float* grz = (float*)smem;          // [32][260]
    float* gin = grz + 32 * 260;        // [32][132]
    float* ghn = gin + 32 * 132;        // [32][132]

    const int t    = threadIdx.x;
    const int wave = t >> 6;
    const int lane = t & 63;
    const int kq   = lane >> 4;
    const int lr   = lane & 15;
    const int n0   = blockIdx.x * 32;

    {
        const int row = t >> 3, c8 = t & 7;
        const int n = min(n0 + row, N_NODES - 1);
        const int so = row * 136 + c8 * 16;
        {
            const float4* ap = (const float4*)(accum + (size_t)n * ND + c8 * 16);
            const float4 a0 = ap[0], a1 = ap[1], a2 = ap[2], a3 = ap[3];
            uint4 h0, h1, l0, l1;
            split2(a0.x, a0.y, h0.x, l0.x); split2(a0.z, a0.w, h0.y, l0.y);
            split2(a1.x, a1.y, h0.z, l0.z); split2(a1.z, a1.w, h0.w, l0.w);
            split2(a2.x, a2.y, h1.x, l1.x); split2(a2.z, a2.w, h1.y, l1.y);
            split2(a3.x, a3.y, h1.z, l1.z); split2(a3.z, a3.w, h1.w, l1.w);
            *(uint4*)(sa_hi + so) = h0;  *(uint4*)(sa_hi + so + 8) = h1;
            *(uint4*)(sa_lo + so) = l0;  *(uint4*)(sa_lo + so + 8) = l1;
        }
        {
            const float4* hp = (const float4*)(h_cur + (size_t)n * ND + c8 * 16);
            const float4 a0 = hp[0], a1 = hp[1], a2 = hp[2], a3 = hp[3];
            uint4 h0, h1, l0, l1;
            split2(a0.x, a0.y, h0.x, l0.x); split2(a0.z, a0.w, h0.y, l0.y);
            split2(a1.x, a1.y, h0.z, l0.z); split2(a1.z, a1.w, h0.w, l0.w);
            split2(a2.x, a2.y, h1.x, l1.x); split2(a2.z, a2.w, h1.y, l1.y);
            split2(a3.x, a3.y, h1.z, l1.z); split2(a3.z, a3.w, h1.w, l1.w);
            *(uint4*)(sh_hi + so) = h0;  *(uint4*)(sh_hi + so + 8) = h1;
            *(uint4*)(sh_lo + so) = l0;  *(uint4*)(sh_lo + so + 8) = l1;
        }
    }
    __syncthreads();

    f32x4 acc_i[2][6], acc_h[2][6];
    #pragma unroll
    for (int m = 0; m < 2; ++m)
        #pragma unroll
        for (int nt = 0; nt < 6; ++nt) {
            acc_i[m][nt] = (f32x4){0.f, 0.f, 0.f, 0.f};
            acc_h[m][nt] = (f32x4){0.f, 0.f, 0.f, 0.f};
        }

    #pragma unroll
    for (int ks = 0; ks < 4; ++ks) {
        bfrag afh[2], afl[2], hfh[2], hfl[2];
        #pragma unroll
        for (int m = 0; m < 2; ++m) {
            const int ao = (m * 16 + lr) * 136 + ks * 32 + kq * 8;
            afh[m] = *(const bfrag*)(sa_hi + ao);
            afl[m] = *(const bfrag*)(sa_lo + ao);
            hfh[m] = *(const bfrag*)(sh_hi + ao);
            hfl[m] = *(const bfrag*)(sh_lo + ao);
        }
        #pragma unroll
        for (int nt = 0; nt < 6; ++nt) {
            const int gnt = wave * 6 + nt;
            const int bo = (((gnt * 4 + ks) * 4 + kq) * 16 + lr) * 8;
            const bfrag bih_h = *(const bfrag*)(Bih_hi + bo);
            const bfrag bih_l = *(const bfrag*)(Bih_lo + bo);
            const bfrag bhh_h = *(const bfrag*)(Bhh_hi + bo);
            const bfrag bhh_l = *(const bfrag*)(Bhh_lo + bo);
            #pragma unroll
            for (int m = 0; m < 2; ++m) {
                acc_i[m][nt] = __builtin_amdgcn_mfma_f32_16x16x32_bf16(afh[m], bih_h, acc_i[m][nt], 0, 0, 0);
                acc_i[m][nt] = __builtin_amdgcn_mfma_f32_16x16x32_bf16(afl[m], bih_h, acc_i[m][nt], 0, 0, 0);
                acc_i[m][nt] = __builtin_amdgcn_mfma_f32_16x16x32_bf16(afh[m], bih_l, acc_i[m][nt], 0, 0, 0);
                acc_h[m][nt] = __builtin_amdgcn_mfma_f32_16x16x32_bf16(hfh[m], bhh_h, acc_h[m][nt], 0, 0, 0);
                acc_h[m][nt] = __builtin_amdgcn_mfma_f32_16x16x32_bf16(hfl[m], bhh_h, acc_h[m][nt], 0, 0, 0);
                acc_h[m][nt] = __builtin_amdgcn_mfma_f32_16x16x32_bf16(hfh[m], bhh_l, acc_h[m][nt], 0, 0, 0);
            }
        }
    }
    __syncthreads();

    #pragma unroll
    for (int nt = 0; nt < 6; ++nt) {
        const int gcol = wave * 96 + nt * 16 + lr;
        if (gcol < 256) {
            const float bias = b_ih[gcol] + b_hh[gcol];
            #pragma unroll
            for (int m = 0; m < 2; ++m)
                #pragma unroll
                for (int r = 0; r < 4; ++r)
                    grz[(m * 16 + kq * 4 + r) * 260 + gcol] =
                        acc_i[m][nt][r] + acc_h[m][nt][r] + bias;
        } else {
            const int cc = gcol - 256;
            const float bi = b_ih[gcol], bh2 = b_hh[gcol];
            #pragma unroll
            for (int m = 0; m < 2; ++m)
                #pragma unroll
                for (int r = 0; r < 4; ++r) {
                    const int rw = m * 16 + kq * 4 + r;
                    gin[rw * 132 + cc] = acc_i[m][nt][r] + bi;
                    ghn[rw * 132 + cc] = acc_h[m][nt][r] + bh2;
                }
        }
    }
    __syncthreads();

    for (int idx = t; idx < 32 * ND; idx += 256) {
        const int nl = idx >> 7, cc = idx & 127;
        const int n = n0 + nl;
        if (n < N_NODES) {
            const float rp  = grz[nl * 260 + cc];
            const float zp  = grz[nl * 260 + 128 + cc];
            const float inp = gin[nl * 132 + cc];
            const float hnp = ghn[nl * 132 + cc];
            const float r = 1.f / (1.f + expf(-rp));
            const float z = 1.f / (1.f + expf(-zp));
            const float nn = tanhf(inp + r * hnp);
            h_out[(size_t)n * ND + cc] =
                (1.f - z) * nn + z * h_cur[(size_t)n * ND + cc];
        }
    }
}

// ---------------------------------------------------------------------------
extern "C" void kernel_launch(void* const* d_in, const int* in_sizes, int n_in,
                              void* d_out, int out_size, void* d_ws, size_t ws_size,
                              hipStream_t stream)
{
    const float* hv   = (const float*)d_in[0];
    const float* he   = (const float*)d_in[1];
    const int*   src  = (const int*)d_in[2];
    const int*   dst  = (const int*)d_in[3];
    const float* Wmsg = (const float*)d_in[4];
    const float* bmsg = (const float*)d_in[5];
    const float* Wih  = (const float*)d_in[6];
    const float* Whh  = (const float*)d_in[7];
    const float* bih  = (const float*)d_in[8];
    const float* bhh  = (const float*)d_in[9];
    float* out = (float*)d_out;

    const int nscan = ((N_NODES + SCAN_BS - 1) / SCAN_BS) * SCAN_BS;  // 50176
    const int nblk  = nscan / SCAN_BS;                                // 98

    char* p = (char*)d_ws;
    float* a_buf = (float*)p;                 p += (size_t)N_NODES * ND * 4;   // 25.6 MB
    ushort_t* S_hi = (ushort_t*)p;            p += (size_t)N_NODES * ND * 2;
    ushort_t* S_lo = (ushort_t*)p;            p += (size_t)N_NODES * ND * 2;
    float* E = (float*)p;                     p += (size_t)N_NODES * ED * 4;   // 6.4 MB
    ushort_t* Wt_hi = (ushort_t*)p;           p += (size_t)2 * AD * CAT * 2;
    ushort_t* Wt_lo = (ushort_t*)p;           p += (size_t)2 * AD * CAT * 2;
    ushort_t* Bih_hi = (ushort_t*)p;          p += (size_t)2 * G3 * ND * 2;
    ushort_t* Bih_lo = (ushort_t*)p;          p += (size_t)2 * G3 * ND * 2;
    ushort_t* Bhh_hi = (ushort_t*)p;          p += (size_t)2 * G3 * ND * 2;
    ushort_t* Bhh_lo = (ushort_t*)p;          p += (size_t)2 * G3 * ND * 2;
    int* deg    = (int*)p;                    p += (size_t)nscan * 4;
    int* rowptr = (int*)p;                    p += (size_t)nscan * 4;
    int* cursor = (int*)p;                    p += (size_t)nscan * 4;
    int* bsum   = (int*)p;                    p += 128 * 4;
    int* perm   = (int*)p;                    p += (size_t)N_EDGES * 4;
    int* src_sorted = (int*)p;                p += (size_t)N_EDGES * 4;

    // ---- once per launch: weights, CSR sort, E, deg ----
    convert_w_kernel<<<(2 * CAT * AD + 255) / 256, 256, 0, stream>>>(Wmsg, Wt_hi, Wt_lo);
    convert_gatew_kernel<<<768, 256, 0, stream>>>(Wih, Whh, Bih_hi, Bih_lo, Bhh_hi, Bhh_lo);

    hipMemsetAsync(deg, 0, (size_t)nscan * 4, stream);
    hist_kernel<<<(N_EDGES + 255) / 256, 256, 0, stream>>>(dst, deg);
    scan_block_kernel<<<nblk, SCAN_BS, 0, stream>>>(deg, rowptr, bsum, nscan);
    scan_sums_kernel<<<1, 128, 0, stream>>>(bsum, nblk);
    scan_add_kernel<<<nblk, SCAN_BS, 0, stream>>>(rowptr, bsum, nscan);
    hipMemcpyAsync(cursor, rowptr, (size_t)nscan * 4, hipMemcpyDeviceToDevice, stream);
    fill_kernel<<<(N_EDGES + 255) / 256, 256, 0, stream>>>(dst, src, cursor, perm, src_sorted);
    esum_kernel<<<(N_NODES * ED + 255) / 256, 256, 0, stream>>>(he, perm, rowptr, E);

    const int tile_blocks = (N_NODES + 31) / 32;   // 1563

    for (int t = 0; t < 2; ++t) {
        const float* h_cur = (t == 0) ? hv : out;
        agg_kernel<<<(N_NODES + 3) / 4, 256, 0, stream>>>(
            h_cur, src_sorted, rowptr, S_hi, S_lo);
        msg_mfma_kernel<<<tile_blocks, 256, 0, stream>>>(
            S_hi, S_lo, h_cur, E, rowptr,
            Wt_hi + (size_t)t * AD * CAT, Wt_lo + (size_t)t * AD * CAT,
            bmsg + (size_t)t * AD, a_buf);
        gru_mfma_kernel<<<tile_blocks, 256, 0, stream>>>(
            a_buf, h_cur,
            Bih_hi + (size_t)t * G3 * ND, Bih_lo + (size_t)t * G3 * ND,
            Bhh_hi + (size_t)t * G3 * ND, Bhh_lo + (size_t)t * G3 * ND,
            bih + (size_t)t * G3, bhh + (size_t)t * G3, out);
    }
}

// Round 7
// 584.292 us; speedup vs baseline: 5.2975x; 1.0990x over previous
//
#include <hip/hip_runtime.h>

#define N_NODES 50000
#define N_EDGES 800000
#define ND 128
#define ED 32
#define AD 128
#define CAT 288   // 2*ND + ED
#define G3 384    // 3*ND

#define XPAD 296      // LDS row stride (bf16 elems), 16B-aligned
#define KSTEPS 9      // 288 / 32
#define SCAN_BS 512

typedef unsigned short ushort_t;
typedef __attribute__((ext_vector_type(8))) short bfrag;   // 8 bf16 (4 VGPRs)
typedef __attribute__((ext_vector_type(4))) float f32x4;   // MFMA accumulator

__device__ __forceinline__ unsigned int f2bf(float f) {
    unsigned int u = __float_as_uint(f);
    return (u + 0x7FFFu + ((u >> 16) & 1u)) >> 16;   // RTNE to bf16
}
__device__ __forceinline__ void split2(float a, float b,
                                       unsigned int& hi, unsigned int& lo) {
    const unsigned int ha = f2bf(a), hb = f2bf(b);
    const float ra = a - __uint_as_float(ha << 16);
    const float rb = b - __uint_as_float(hb << 16);
    hi = ha | (hb << 16);
    lo = f2bf(ra) | (f2bf(rb) << 16);
}
__device__ __forceinline__ void split1(float a, ushort_t& hi, ushort_t& lo) {
    const unsigned int ha = f2bf(a);
    const float ra = a - __uint_as_float(ha << 16);
    hi = (ushort_t)ha;
    lo = (ushort_t)f2bf(ra);
}

// ========================= counting sort by dst ============================
__global__ __launch_bounds__(256) void hist_kernel(
    const int* __restrict__ dst, int* __restrict__ deg)
{
    const int e = blockIdx.x * 256 + threadIdx.x;
    if (e < N_EDGES) atomicAdd(&deg[dst[e]], 1);
}

__global__ __launch_bounds__(SCAN_BS) void scan_block_kernel(
    const int* __restrict__ in, int* __restrict__ out,
    int* __restrict__ bsum, int n)
{
    __shared__ int s[SCAN_BS];
    const int g = blockIdx.x * SCAN_BS + threadIdx.x;
    const int v = (g < n) ? in[g] : 0;
    s[threadIdx.x] = v;
    __syncthreads();
    for (int off = 1; off < SCAN_BS; off <<= 1) {
        const int x = (threadIdx.x >= off) ? s[threadIdx.x - off] : 0;
        __syncthreads();
        s[threadIdx.x] += x;
        __syncthreads();
    }
    if (g < n) out[g] = s[threadIdx.x] - v;   // exclusive
    if (threadIdx.x == SCAN_BS - 1) bsum[blockIdx.x] = s[threadIdx.x];
}

__global__ __launch_bounds__(128) void scan_sums_kernel(int* __restrict__ bsum, int nb)
{
    __shared__ int s[128];
    const int i = threadIdx.x;
    s[i] = (i < nb) ? bsum[i] : 0;
    __syncthreads();
    if (i == 0) {
        int acc = 0;
        for (int k = 0; k < nb; ++k) { const int t = s[k]; s[k] = acc; acc += t; }
    }
    __syncthreads();
    if (i < nb) bsum[i] = s[i];
}

// writes final rowptr AND an identical cursor copy (fill destroys cursor).
__global__ __launch_bounds__(SCAN_BS) void scan_add_kernel(
    int* __restrict__ rowptr, int* __restrict__ cursor,
    const int* __restrict__ bsum, int n)
{
    const int g = blockIdx.x * SCAN_BS + threadIdx.x;
    if (g < n) {
        const int v = rowptr[g] + bsum[blockIdx.x];
        rowptr[g] = v;
        cursor[g] = v;
    }
}

__global__ __launch_bounds__(256) void fill_kernel(
    const int* __restrict__ dst, const int* __restrict__ src,
    int* __restrict__ cursor, int* __restrict__ perm,
    int* __restrict__ src_sorted)
{
    const int e = blockIdx.x * 256 + threadIdx.x;
    if (e < N_EDGES) {
        const int p = atomicAdd(&cursor[dst[e]], 1);
        perm[p] = e;
        src_sorted[p] = src[e];
    }
}

// E[v] = sum of he rows over in-edges of v. 4-way unrolled independent gathers.
__global__ __launch_bounds__(256) void esum_kernel(
    const float* __restrict__ he, const int* __restrict__ perm,
    const int* __restrict__ rowptr, float* __restrict__ E)
{
    const int id = blockIdx.x * 256 + threadIdx.x;   // N_NODES*32 ids
    if (id >= N_NODES * ED) return;
    const int v = id >> 5, c = id & 31;
    const int r0 = rowptr[v], r1 = rowptr[v + 1];
    float s = 0.f;
    int i = r0;
    for (; i + 4 <= r1; i += 4) {
        const int p0 = perm[i],     p1 = perm[i + 1];
        const int p2 = perm[i + 2], p3 = perm[i + 3];
        const float a = he[(size_t)p0 * ED + c];
        const float b = he[(size_t)p1 * ED + c];
        const float d = he[(size_t)p2 * ED + c];
        const float f = he[(size_t)p3 * ED + c];
        s += (a + b) + (d + f);
    }
    for (; i < r1; ++i)
        s += he[(size_t)perm[i] * ED + c];
    E[(size_t)v * ED + c] = s;
}

// ========================= weight converts (once) ==========================
__global__ __launch_bounds__(256) void convert_w_kernel(
    const float* __restrict__ W,
    ushort_t* __restrict__ Wt_hi, ushort_t* __restrict__ Wt_lo)
{
    const int id = blockIdx.x * 256 + threadIdx.x;   // 2*288*128 = 73728
    if (id >= 2 * CAT * AD) return;
    const int n = id & (AD - 1);
    const int k = (id >> 7) % CAT;
    const int t = id / (CAT * AD);
    const float w = W[(size_t)t * CAT * AD + (size_t)k * AD + n];
    const unsigned int hi = f2bf(w);
    const float r = w - __uint_as_float(hi << 16);
    const size_t o = (size_t)t * AD * CAT + (size_t)n * CAT + k;
    Wt_hi[o] = (ushort_t)hi;
    Wt_lo[o] = (ushort_t)f2bf(r);
}

__global__ __launch_bounds__(256) void convert_gatew_kernel(
    const float* __restrict__ W_ih, const float* __restrict__ W_hh,
    ushort_t* __restrict__ Bih_hi, ushort_t* __restrict__ Bih_lo,
    ushort_t* __restrict__ Bhh_hi, ushort_t* __restrict__ Bhh_lo)
{
    const int id = blockIdx.x * 256 + threadIdx.x;   // 196608
    if (id >= 196608) return;
    const int t   = id / 98304;
    const int rem = id % 98304;
    const int mat = rem / 49152;
    const int q   = rem % 49152;
    const int nt = q / 2048,  r1 = q % 2048;
    const int ks = r1 / 512,  r2 = r1 % 512;
    const int kq = r2 / 128,  r3 = r2 % 128;
    const int lr = r3 / 8,    j  = r3 % 8;
    const int n = nt * 16 + lr;
    const int k = ks * 32 + kq * 8 + j;
    const float* W = mat ? W_hh : W_ih;
    const float w = W[(size_t)t * ND * G3 + (size_t)k * G3 + n];
    const unsigned int hi = f2bf(w);
    const float res = w - __uint_as_float(hi << 16);
    const size_t o = (size_t)t * 49152 + q;
    if (mat) { Bhh_hi[o] = (ushort_t)hi; Bhh_lo[o] = (ushort_t)f2bf(res); }
    else     { Bih_hi[o] = (ushort_t)hi; Bih_lo[o] = (ushort_t)f2bf(res); }
}

// ---------------------------------------------------------------------------
// Aggregation: S[v] = sum over in-edges of hv[src_e] (fp32), pre-split bf16.
// One wave per node; lane = 2 cols; 8x unrolled independent gathers.
// ---------------------------------------------------------------------------
__global__ __launch_bounds__(256) void agg_kernel(
    const float* __restrict__ hv, const int* __restrict__ src_sorted,
    const int* __restrict__ rowptr,
    ushort_t* __restrict__ S_hi, ushort_t* __restrict__ S_lo)
{
    const int v = blockIdx.x * 4 + (threadIdx.x >> 6);
    if (v >= N_NODES) return;
    const int lane = threadIdx.x & 63;
    const int r0 = rowptr[v], r1 = rowptr[v + 1];
    const float2* hv2 = (const float2*)hv;
    float sx = 0.f, sy = 0.f;
    int i = r0;
    for (; i + 8 <= r1; i += 8) {
        const int s0 = src_sorted[i],     s1 = src_sorted[i + 1];
        const int s2 = src_sorted[i + 2], s3 = src_sorted[i + 3];
        const int s4 = src_sorted[i + 4], s5 = src_sorted[i + 5];
        const int s6 = src_sorted[i + 6], s7 = src_sorted[i + 7];
        const float2 a = hv2[(size_t)s0 * 64 + lane];
        const float2 b = hv2[(size_t)s1 * 64 + lane];
        const float2 c = hv2[(size_t)s2 * 64 + lane];
        const float2 d = hv2[(size_t)s3 * 64 + lane];
        const float2 e = hv2[(size_t)s4 * 64 + lane];
        const float2 f = hv2[(size_t)s5 * 64 + lane];
        const float2 g = hv2[(size_t)s6 * 64 + lane];
        const float2 h = hv2[(size_t)s7 * 64 + lane];
        sx += ((a.x + b.x) + (c.x + d.x)) + ((e.x + f.x) + (g.x + h.x));
        sy += ((a.y + b.y) + (c.y + d.y)) + ((e.y + f.y) + (g.y + h.y));
    }
    for (; i < r1; ++i) {
        const float2 a = hv2[(size_t)src_sorted[i] * 64 + lane];
        sx += a.x; sy += a.y;
    }
    unsigned int h, l;
    split2(sx, sy, h, l);
    ((unsigned int*)S_hi)[(size_t)v * 64 + lane] = h;
    ((unsigned int*)S_lo)[(size_t)v * 64 + lane] = l;
}

// ---------------------------------------------------------------------------
// Fused msg+GRU kernel (MFMA, bf16x2). Per 32-node tile:
//   A: stage X=[S|deg*h|E] (hi/lo) + h fragments (hi/lo)
//   B: a = X @ Wmsg  (4 accs/wave)
//   C: a + deg*bias -> split -> GRU A-fragment LDS (aliases X region)
//   D: gi = a@W_ih, gh = h@W_hh (B frags streamed from L2, swizzled)
//   E: gates -> h_out
// ---------------------------------------------------------------------------
__global__ __launch_bounds__(256, 2) void fused_msg_gru_kernel(
    const ushort_t* __restrict__ S_hi, const ushort_t* __restrict__ S_lo,
    const float* __restrict__ h_cur, const float* __restrict__ E,
    const int* __restrict__ rowptr,
    const ushort_t* __restrict__ Wt_hi, const ushort_t* __restrict__ Wt_lo,
    const float* __restrict__ bmsg,
    const ushort_t* __restrict__ Bih_hi, const ushort_t* __restrict__ Bih_lo,
    const ushort_t* __restrict__ Bhh_hi, const ushort_t* __restrict__ Bhh_lo,
    const float* __restrict__ b_ih, const float* __restrict__ b_hh,
    float* __restrict__ h_out)
{
    __shared__ __align__(16) char smem[67072];
    // phase A/B layout:
    ushort_t* xh    = (ushort_t*)smem;           // [32][296] = 18944 B
    ushort_t* xl    = xh + 32 * XPAD;            // [32][296] = 18944 B
    ushort_t* sh_hi = xl + 32 * XPAD;            // [32][136] =  8704 B
    ushort_t* sh_lo = sh_hi + 32 * 136;          // [32][136] =  8704 B  (55296 total)
    // phase C/D: sa aliases xh/xl region (a-fragments)
    ushort_t* sa_hi = (ushort_t*)smem;           // [32][136]
    ushort_t* sa_lo = sa_hi + 32 * 136;          // [32][136]
    // phase E: gate pre-activations alias everything
    float* grz = (float*)smem;                   // [32][260]
    float* gin = grz + 32 * 260;                 // [32][132]
    float* ghn = gin + 32 * 132;                 // [32][132]
    __shared__ float sdeg[32];

    const int t    = threadIdx.x;
    const int wave = t >> 6;
    const int lane = t & 63;
    const int kq   = lane >> 4;
    const int lr   = lane & 15;
    const int n0   = blockIdx.x * 32;

    // ---- msg B fragments (register resident through phase B) ----
    bfrag mbh[2][KSTEPS], mbl[2][KSTEPS];
    float mbias[2];
    #pragma unroll
    for (int nt = 0; nt < 2; ++nt) {
        const int n = wave * 32 + nt * 16 + lr;
        mbias[nt] = bmsg[n];
        const ushort_t* ph = Wt_hi + (size_t)n * CAT + kq * 8;
        const ushort_t* pl = Wt_lo + (size_t)n * CAT + kq * 8;
        #pragma unroll
        for (int ks = 0; ks < KSTEPS; ++ks) {
            mbh[nt][ks] = *(const bfrag*)(ph + ks * 32);
            mbl[nt][ks] = *(const bfrag*)(pl + ks * 32);
        }
    }

    // ---- phase A: stage X and h ----
    {
        const int row = t >> 3, c8 = t & 7;
        const int n = min(n0 + row, N_NODES - 1);
        if (t < 32) {
            const int nn = min(n0 + t, N_NODES - 1);
            sdeg[t] = (float)(rowptr[nn + 1] - rowptr[nn]);
        }
        // S: pre-split copies
        {
            const uint4* ph = (const uint4*)(S_hi + (size_t)n * ND + c8 * 16);
            const uint4* pl = (const uint4*)(S_lo + (size_t)n * ND + c8 * 16);
            *(uint4*)&xh[row * XPAD + c8 * 16]     = ph[0];
            *(uint4*)&xh[row * XPAD + c8 * 16 + 8] = ph[1];
            *(uint4*)&xl[row * XPAD + c8 * 16]     = pl[0];
            *(uint4*)&xl[row * XPAD + c8 * 16 + 8] = pl[1];
        }
        // h: one fp32 load serves deg*h (X) and h (GRU operand)
        {
            const float degf = (float)(rowptr[n + 1] - rowptr[n]);
            const float4* hp = (const float4*)(h_cur + (size_t)n * ND + c8 * 16);
            const float4 v0 = hp[0], v1 = hp[1], v2 = hp[2], v3 = hp[3];
            // unscaled h fragments
            uint4 h0, h1, l0, l1;
            split2(v0.x, v0.y, h0.x, l0.x); split2(v0.z, v0.w, h0.y, l0.y);
            split2(v1.x, v1.y, h0.z, l0.z); split2(v1.z, v1.w, h0.w, l0.w);
            split2(v2.x, v2.y, h1.x, l1.x); split2(v2.z, v2.w, h1.y, l1.y);
            split2(v3.x, v3.y, h1.z, l1.z); split2(v3.z, v3.w, h1.w, l1.w);
            const int so = row * 136 + c8 * 16;
            *(uint4*)(sh_hi + so) = h0;  *(uint4*)(sh_hi + so + 8) = h1;
            *(uint4*)(sh_lo + so) = l0;  *(uint4*)(sh_lo + so + 8) = l1;
            // deg*h
            uint4 g0, g1, m0, m1;
            split2(v0.x * degf, v0.y * degf, g0.x, m0.x); split2(v0.z * degf, v0.w * degf, g0.y, m0.y);
            split2(v1.x * degf, v1.y * degf, g0.z, m0.z); split2(v1.z * degf, v1.w * degf, g0.w, m0.w);
            split2(v2.x * degf, v2.y * degf, g1.x, m1.x); split2(v2.z * degf, v2.w * degf, g1.y, m1.y);
            split2(v3.x * degf, v3.y * degf, g1.z, m1.z); split2(v3.z * degf, v3.w * degf, g1.w, m1.w);
            *(uint4*)&xh[row * XPAD + ND + c8 * 16]     = g0;
            *(uint4*)&xh[row * XPAD + ND + c8 * 16 + 8] = g1;
            *(uint4*)&xl[row * XPAD + ND + c8 * 16]     = m0;
            *(uint4*)&xl[row * XPAD + ND + c8 * 16 + 8] = m1;
        }
        // E: 4 floats
        {
            const float4 e4 = *(const float4*)(E + (size_t)n * ED + c8 * 4);
            uint2 h0, l0;
            split2(e4.x, e4.y, h0.x, l0.x); split2(e4.z, e4.w, h0.y, l0.y);
            *(uint2*)&xh[row * XPAD + 2 * ND + c8 * 4] = h0;
            *(uint2*)&xl[row * XPAD + 2 * ND + c8 * 4] = l0;
        }
    }
    __syncthreads();

    // ---- phase B: msg MFMA ----
    f32x4 acc00 = {0.f,0.f,0.f,0.f}, acc01 = {0.f,0.f,0.f,0.f};
    f32x4 acc10 = {0.f,0.f,0.f,0.f}, acc11 = {0.f,0.f,0.f,0.f};
    #pragma unroll
    for (int ks = 0; ks < KSTEPS; ++ks) {
        const int ko = ks * 32 + kq * 8;
        const bfrag a0h = *(const bfrag*)&xh[lr * XPAD + ko];
        const bfrag a0l = *(const bfrag*)&xl[lr * XPAD + ko];
        const bfrag a1h = *(const bfrag*)&xh[(16 + lr) * XPAD + ko];
        const bfrag a1l = *(const bfrag*)&xl[(16 + lr) * XPAD + ko];
        acc00 = __builtin_amdgcn_mfma_f32_16x16x32_bf16(a0h, mbh[0][ks], acc00, 0, 0, 0);
        acc00 = __builtin_amdgcn_mfma_f32_16x16x32_bf16(a0l, mbh[0][ks], acc00, 0, 0, 0);
        acc00 = __builtin_amdgcn_mfma_f32_16x16x32_bf16(a0h, mbl[0][ks], acc00, 0, 0, 0);
        acc01 = __builtin_amdgcn_mfma_f32_16x16x32_bf16(a0h, mbh[1][ks], acc01, 0, 0, 0);
        acc01 = __builtin_amdgcn_mfma_f32_16x16x32_bf16(a0l, mbh[1][ks], acc01, 0, 0, 0);
        acc01 = __builtin_amdgcn_mfma_f32_16x16x32_bf16(a0h, mbl[1][ks], acc01, 0, 0, 0);
        acc10 = __builtin_amdgcn_mfma_f32_16x16x32_bf16(a1h, mbh[0][ks], acc10, 0, 0, 0);
        acc10 = __builtin_amdgcn_mfma_f32_16x16x32_bf16(a1l, mbh[0][ks], acc10, 0, 0, 0);
        acc10 = __builtin_amdgcn_mfma_f32_16x16x32_bf16(a1h, mbl[0][ks], acc10, 0, 0, 0);
        acc11 = __builtin_amdgcn_mfma_f32_16x16x32_bf16(a1h, mbh[1][ks], acc11, 0, 0, 0);
        acc11 = __builtin_amdgcn_mfma_f32_16x16x32_bf16(a1l, mbh[1][ks], acc11, 0, 0, 0);
        acc11 = __builtin_amdgcn_mfma_f32_16x16x32_bf16(a1h, mbl[1][ks], acc11, 0, 0, 0);
    }
    __syncthreads();   // xh/xl reads complete before aliasing writes

    // ---- phase C: a = acc + deg*bias -> split -> GRU A-fragment LDS ----
    #pragma unroll
    for (int r = 0; r < 4; ++r) {
        const int row0 = kq * 4 + r;
        const int row1 = 16 + kq * 4 + r;
        const int c0 = wave * 32 + lr, c1 = wave * 32 + 16 + lr;
        ushort_t h, l;
        split1(acc00[r] + sdeg[row0] * mbias[0], h, l);
        sa_hi[row0 * 136 + c0] = h; sa_lo[row0 * 136 + c0] = l;
        split1(acc01[r] + sdeg[row0] * mbias[1], h, l);
        sa_hi[row0 * 136 + c1] = h; sa_lo[row0 * 136 + c1] = l;
        split1(acc10[r] + sdeg[row1] * mbias[0], h, l);
        sa_hi[row1 * 136 + c0] = h; sa_lo[row1 * 136 + c0] = l;
        split1(acc11[r] + sdeg[row1] * mbias[1], h, l);
        sa_hi[row1 * 136 + c1] = h; sa_lo[row1 * 136 + c1] = l;
    }
    __syncthreads();

    // ---- phase D: GRU MFMA ----
    f32x4 acc_i[2][6], acc_h[2][6];
    #pragma unroll
    for (int m = 0; m < 2; ++m)
        #pragma unroll
        for (int nt = 0; nt < 6; ++nt) {
            acc_i[m][nt] = (f32x4){0.f, 0.f, 0.f, 0.f};
            acc_h[m][nt] = (f32x4){0.f, 0.f, 0.f, 0.f};
        }

    #pragma unroll
    for (int ks = 0; ks < 4; ++ks) {
        bfrag afh[2], afl[2], hfh[2], hfl[2];
        #pragma unroll
        for (int m = 0; m < 2; ++m) {
            const int ao = (m * 16 + lr) * 136 + ks * 32 + kq * 8;
            afh[m] = *(const bfrag*)(sa_hi + ao);
            afl[m] = *(const bfrag*)(sa_lo + ao);
            hfh[m] = *(const bfrag*)(sh_hi + ao);
            hfl[m] = *(const bfrag*)(sh_lo + ao);
        }
        #pragma unroll
        for (int nt = 0; nt < 6; ++nt) {
            const int gnt = wave * 6 + nt;
            const int bo = (((gnt * 4 + ks) * 4 + kq) * 16 + lr) * 8;
            const bfrag bih_h = *(const bfrag*)(Bih_hi + bo);
            const bfrag bih_l = *(const bfrag*)(Bih_lo + bo);
            const bfrag bhh_h = *(const bfrag*)(Bhh_hi + bo);
            const bfrag bhh_l = *(const bfrag*)(Bhh_lo + bo);
            #pragma unroll
            for (int m = 0; m < 2; ++m) {
                acc_i[m][nt] = __builtin_amdgcn_mfma_f32_16x16x32_bf16(afh[m], bih_h, acc_i[m][nt], 0, 0, 0);
                acc_i[m][nt] = __builtin_amdgcn_mfma_f32_16x16x32_bf16(afl[m], bih_h, acc_i[m][nt], 0, 0, 0);
                acc_i[m][nt] = __builtin_amdgcn_mfma_f32_16x16x32_bf16(afh[m], bih_l, acc_i[m][nt], 0, 0, 0);
                acc_h[m][nt] = __builtin_amdgcn_mfma_f32_16x16x32_bf16(hfh[m], bhh_h, acc_h[m][nt], 0, 0, 0);
                acc_h[m][nt] = __builtin_amdgcn_mfma_f32_16x16x32_bf16(hfl[m], bhh_h, acc_h[m][nt], 0, 0, 0);
                acc_h[m][nt] = __builtin_amdgcn_mfma_f32_16x16x32_bf16(hfh[m], bhh_l, acc_h[m][nt], 0, 0, 0);
            }
        }
    }
    __syncthreads();   // sa/sh reads complete before gate aliasing writes

    // ---- phase E: gate pre-activations ----
    #pragma unroll
    for (int nt = 0; nt < 6; ++nt) {
        const int gcol = wave * 96 + nt * 16 + lr;
        if (gcol < 256) {
            const float bias = b_ih[gcol] + b_hh[gcol];
            #pragma unroll
            for (int m = 0; m < 2; ++m)
                #pragma unroll
                for (int r = 0; r < 4; ++r)
                    grz[(m * 16 + kq * 4 + r) * 260 + gcol] =
                        acc_i[m][nt][r] + acc_h[m][nt][r] + bias;
        } else {
            const int cc = gcol - 256;
            const float bi = b_ih[gcol], bh2 = b_hh[gcol];
            #pragma unroll
            for (int m = 0; m < 2; ++m)
                #pragma unroll
                for (int r = 0; r < 4; ++r) {
                    const int rw = m * 16 + kq * 4 + r;
                    gin[rw * 132 + cc] = acc_i[m][nt][r] + bi;
                    ghn[rw * 132 + cc] = acc_h[m][nt][r] + bh2;
                }
        }
    }
    __syncthreads();

    for (int idx = t; idx < 32 * ND; idx += 256) {
        const int nl = idx >> 7, cc = idx & 127;
        const int n = n0 + nl;
        if (n < N_NODES) {
            const float rp  = grz[nl * 260 + cc];
            const float zp  = grz[nl * 260 + 128 + cc];
            const float inp = gin[nl * 132 + cc];
            const float hnp = ghn[nl * 132 + cc];
            const float r = 1.f / (1.f + expf(-rp));
            const float z = 1.f / (1.f + expf(-zp));
            const float nn = tanhf(inp + r * hnp);
            h_out[(size_t)n * ND + cc] =
                (1.f - z) * nn + z * h_cur[(size_t)n * ND + cc];
        }
    }
}

// ---------------------------------------------------------------------------
extern "C" void kernel_launch(void* const* d_in, const int* in_sizes, int n_in,
                              void* d_out, int out_size, void* d_ws, size_t ws_size,
                              hipStream_t stream)
{
    const float* hv   = (const float*)d_in[0];
    const float* he   = (const float*)d_in[1];
    const int*   src  = (const int*)d_in[2];
    const int*   dst  = (const int*)d_in[3];
    const float* Wmsg = (const float*)d_in[4];
    const float* bmsg = (const float*)d_in[5];
    const float* Wih  = (const float*)d_in[6];
    const float* Whh  = (const float*)d_in[7];
    const float* bih  = (const float*)d_in[8];
    const float* bhh  = (const float*)d_in[9];
    float* out = (float*)d_out;

    const int nscan = ((N_NODES + SCAN_BS - 1) / SCAN_BS) * SCAN_BS;  // 50176
    const int nblk  = nscan / SCAN_BS;                                // 98

    char* p = (char*)d_ws;
    ushort_t* S_hi = (ushort_t*)p;            p += (size_t)N_NODES * ND * 2;
    ushort_t* S_lo = (ushort_t*)p;            p += (size_t)N_NODES * ND * 2;
    float* E = (float*)p;                     p += (size_t)N_NODES * ED * 4;   // 6.4 MB
    ushort_t* Wt_hi = (ushort_t*)p;           p += (size_t)2 * AD * CAT * 2;
    ushort_t* Wt_lo = (ushort_t*)p;           p += (size_t)2 * AD * CAT * 2;
    ushort_t* Bih_hi = (ushort_t*)p;          p += (size_t)2 * G3 * ND * 2;
    ushort_t* Bih_lo = (ushort_t*)p;          p += (size_t)2 * G3 * ND * 2;
    ushort_t* Bhh_hi = (ushort_t*)p;          p += (size_t)2 * G3 * ND * 2;
    ushort_t* Bhh_lo = (ushort_t*)p;          p += (size_t)2 * G3 * ND * 2;
    int* deg    = (int*)p;                    p += (size_t)nscan * 4;
    int* rowptr = (int*)p;                    p += (size_t)nscan * 4;
    int* cursor = (int*)p;                    p += (size_t)nscan * 4;
    int* bsum   = (int*)p;                    p += 128 * 4;
    int* perm   = (int*)p;                    p += (size_t)N_EDGES * 4;
    int* src_sorted = (int*)p;                p += (size_t)N_EDGES * 4;

    // ---- once per launch: weights, CSR sort, E ----
    convert_w_kernel<<<(2 * CAT * AD + 255) / 256, 256, 0, stream>>>(Wmsg, Wt_hi, Wt_lo);
    convert_gatew_kernel<<<768, 256, 0, stream>>>(Wih, Whh, Bih_hi, Bih_lo, Bhh_hi, Bhh_lo);

    hipMemsetAsync(deg, 0, (size_t)nscan * 4, stream);
    hist_kernel<<<(N_EDGES + 255) / 256, 256, 0, stream>>>(dst, deg);
    scan_block_kernel<<<nblk, SCAN_BS, 0, stream>>>(deg, rowptr, bsum, nscan);
    scan_sums_kernel<<<1, 128, 0, stream>>>(bsum, nblk);
    scan_add_kernel<<<nblk, SCAN_BS, 0, stream>>>(rowptr, cursor, bsum, nscan);
    fill_kernel<<<(N_EDGES + 255) / 256, 256, 0, stream>>>(dst, src, cursor, perm, src_sorted);
    esum_kernel<<<(N_NODES * ED + 255) / 256, 256, 0, stream>>>(he, perm, rowptr, E);

    const int tile_blocks = (N_NODES + 31) / 32;   // 1563

    for (int t = 0; t < 2; ++t) {
        const float* h_cur = (t == 0) ? hv : out;
        agg_kernel<<<(N_NODES + 3) / 4, 256, 0, stream>>>(
            h_cur, src_sorted, rowptr, S_hi, S_lo);
        fused_msg_gru_kernel<<<tile_blocks, 256, 0, stream>>>(
            S_hi, S_lo, h_cur, E, rowptr,
            Wt_hi + (size_t)t * AD * CAT, Wt_lo + (size_t)t * AD * CAT,
            bmsg + (size_t)t * AD,
            Bih_hi + (size_t)t * G3 * ND, Bih_lo + (size_t)t * G3 * ND,
            Bhh_hi + (size_t)t * G3 * ND, Bhh_lo + (size_t)t * G3 * ND,
            bih + (size_t)t * G3, bhh + (size_t)t * G3, out);
    }
}